// Round 3
// baseline (1525.838 us; speedup 1.0000x reference)
//
#include <hip/hip_runtime.h>

// Problem constants (fixed by the reference file)
constexpr int D_IN  = 128;
constexpr int D_OUT = 64;
constexpr int NCH   = 2;
constexpr int NUM_A = 4;
constexpr int COLS  = NCH * D_OUT;     // 128 bf16 per Hc row (ch0 64 | ch1 64)
constexpr int RPB   = 64;              // rows per bucket
constexpr int MAXNB = 800;             // LDS cap (N up to 51200)
constexpr int HPAD  = 130;             // gemm LDS row stride (breaks bank conflicts)

__device__ inline unsigned short f2bf_rn(float f) {
    unsigned u = __float_as_uint(f);
    return (unsigned short)((u + 0x7fffu + ((u >> 16) & 1u)) >> 16);
}
__device__ inline float bf_lo(unsigned u) { return __uint_as_float(u << 16); }
__device__ inline float bf_hi(unsigned u) { return __uint_as_float(u & 0xffff0000u); }

// ---------------------------------------------------------------------------
// Kernel 1: score[c][a] = 0.5 * softmax_a( mean_d att[c][d][a] )
// ---------------------------------------------------------------------------
__global__ __launch_bounds__(64) void score_kernel(const float* __restrict__ att,
                                                   float* __restrict__ score) {
    int lane = threadIdx.x;
    int c = lane >> 2, a = lane & 3;
    float s = 0.0f;
    if (lane < 8) {
        const float* p = att + c * (D_IN * NUM_A) + a;
        for (int d = 0; d < D_IN; ++d) s += p[d * NUM_A];
        s *= (1.0f / D_IN);
    }
    float m = fmaxf(s, __shfl_xor(s, 1));
    m = fmaxf(m, __shfl_xor(m, 2));
    float ex = __expf(s - m);
    float sum = ex + __shfl_xor(ex, 1);
    sum += __shfl_xor(sum, 2);
    if (lane < 8) score[lane] = 0.5f * ex / sum;   // fold the channel-mean 0.5 in
}

// ---------------------------------------------------------------------------
// Kernel 2: Hc[n][c*64+o] = sum_k H[n][k]*W[c][k][o], output bf16
// ---------------------------------------------------------------------------
__global__ __launch_bounds__(256) void gemm_kernel(const float* __restrict__ H,
                                                   const float* __restrict__ W,
                                                   unsigned short* __restrict__ Hc, int N) {
    __shared__ float Hs[32 * HPAD];          // 16.25 KB, stride 130 breaks conflicts
    const int t    = threadIdx.x;
    const int row0 = blockIdx.x * 32;
    const int nvalid = min(32, N - row0);

    const float4* src = reinterpret_cast<const float4*>(H + (size_t)row0 * D_IN);
    for (int i = t; i < nvalid * 32; i += 256) {
        const int r = i >> 5, q = i & 31;
        float4 v = src[(size_t)r * 32 + q];
        float2* d = reinterpret_cast<float2*>(&Hs[r * HPAD + q * 4]);
        d[0] = make_float2(v.x, v.y);
        d[1] = make_float2(v.z, v.w);
    }
    __syncthreads();

    const int pair = t & 63;
    const int rg   = t >> 6;
    const int co0  = pair * 2;
    const int c    = co0 >> 6;
    const int o    = co0 & 63;

    const float* Wp = W + c * (D_IN * D_OUT) + o;
    const float* hs = Hs + rg * 8 * HPAD;

    float acc[8][2];
    #pragma unroll
    for (int r = 0; r < 8; ++r) { acc[r][0] = 0.f; acc[r][1] = 0.f; }

    #pragma unroll 4
    for (int k = 0; k < D_IN; ++k) {
        const float2 w = *reinterpret_cast<const float2*>(Wp + k * D_OUT);
        #pragma unroll
        for (int r = 0; r < 8; ++r) {
            const float h = hs[r * HPAD + k];
            acc[r][0] += h * w.x;
            acc[r][1] += h * w.y;
        }
    }

    #pragma unroll
    for (int r = 0; r < 8; ++r) {
        const int row = row0 + rg * 8 + r;
        if (row < N) {
            unsigned pk = (unsigned)f2bf_rn(acc[r][0]) | ((unsigned)f2bf_rn(acc[r][1]) << 16);
            *reinterpret_cast<unsigned*>(Hc + (size_t)row * COLS + co0) = pk;
        }
    }
}

// ---------------------------------------------------------------------------
// Kernel 3: LDS-aggregated histogram of buckets (bucket = row >> 6)
// ---------------------------------------------------------------------------
__global__ __launch_bounds__(1024) void hist_kernel(const int* __restrict__ rows,
                                                    unsigned* __restrict__ counts,
                                                    int TE, int NB) {
    __shared__ unsigned h[MAXNB];
    const int t = threadIdx.x;
    for (int i = t; i < MAXNB; i += 1024) h[i] = 0u;
    __syncthreads();
    for (int e = blockIdx.x * 1024 + t; e < TE; e += gridDim.x * 1024)
        atomicAdd(&h[rows[e] >> 6], 1u);
    __syncthreads();
    for (int i = t; i < NB; i += 1024)
        if (h[i]) atomicAdd(&counts[i], h[i]);
}

// ---------------------------------------------------------------------------
// Kernel 4: exclusive scan of counts -> offsets (and cursor copy). 1 block.
// ---------------------------------------------------------------------------
__global__ __launch_bounds__(1024) void scan_kernel(const unsigned* __restrict__ counts,
                                                    unsigned* __restrict__ offsets,
                                                    unsigned* __restrict__ cursor, int n) {
    __shared__ unsigned part[1024];
    const int t = threadIdx.x;
    const int chunk = (n + 1023) >> 10;
    const int s = t * chunk;
    const int e = min(s + chunk, n);
    unsigned sum = 0;
    for (int i = s; i < e; ++i) sum += counts[i];
    part[t] = sum;
    __syncthreads();
    for (int d = 1; d < 1024; d <<= 1) {
        unsigned v = (t >= d) ? part[t - d] : 0u;
        __syncthreads();
        part[t] += v;
        __syncthreads();
    }
    unsigned run = (t == 0) ? 0u : part[t - 1];
    for (int i = s; i < e; ++i) {
        const unsigned c = counts[i];
        offsets[i] = run;
        cursor[i]  = run;
        run += c;
    }
}

// ---------------------------------------------------------------------------
// Kernel 5: LDS-aggregated scatter into bucket-major records.
// record.x = col | (row_in_bucket << 16); record.y = bf16(w0) | bf16(w1)<<16
// One return-atomic per (block,bucket); block's range per bucket contiguous.
// ---------------------------------------------------------------------------
constexpr int SC_T   = 512;
constexpr int SC_EPT = 8;
constexpr int SC_CH  = SC_T * SC_EPT;   // 4096 edges per block

__global__ __launch_bounds__(SC_T) void scatter_kernel(const int* __restrict__ rows,
                                                       const int* __restrict__ cols,
                                                       const float* __restrict__ vals,
                                                       const float* __restrict__ score,
                                                       unsigned* __restrict__ cursor,
                                                       uint2* __restrict__ erec,
                                                       int TE, int Eper, int NB) {
    __shared__ unsigned lh[MAXNB];     // local hist, then local cursor
    __shared__ unsigned base[MAXNB];   // claimed global base
    const int t  = threadIdx.x;
    const int e0 = blockIdx.x * SC_CH;

    for (int i = t; i < MAXNB; i += SC_T) lh[i] = 0u;
    __syncthreads();

    int   rw[SC_EPT]; int cl[SC_EPT]; float w0[SC_EPT], w1[SC_EPT];
    #pragma unroll
    for (int k = 0; k < SC_EPT; ++k) {
        const int e = e0 + k * SC_T + t;
        rw[k] = -1;
        if (e < TE) {
            rw[k] = rows[e];
            cl[k] = cols[e];
            const float v = vals[e];
            const int  a = e / Eper;
            w0[k] = score[a] * v;
            w1[k] = score[4 + a] * v;
            atomicAdd(&lh[rw[k] >> 6], 1u);
        }
    }
    __syncthreads();

    for (int i = t; i < NB; i += SC_T) {
        const unsigned c = lh[i];
        base[i] = c ? atomicAdd(&cursor[i], c) : 0u;
        lh[i] = 0u;                    // reuse as local cursor
    }
    __syncthreads();

    #pragma unroll
    for (int k = 0; k < SC_EPT; ++k) {
        if (rw[k] >= 0) {
            const int b   = rw[k] >> 6;
            const unsigned rank = atomicAdd(&lh[b], 1u);
            const unsigned pos  = base[b] + rank;
            const unsigned meta = (unsigned)cl[k] | ((unsigned)(rw[k] & 63) << 16);
            const unsigned wpk  = (unsigned)f2bf_rn(w0[k]) | ((unsigned)f2bf_rn(w1[k]) << 16);
            erec[pos] = make_uint2(meta, wpk);
        }
    }
}

// ---------------------------------------------------------------------------
// Kernel 6: bucket-SpMM. One block per bucket; 64x64 f32 accumulator in LDS
// (stride 65); 16 lanes per edge; LDS f32 atomics; plain coalesced store
// (covers zero-init of d_out).
// ---------------------------------------------------------------------------
__global__ __launch_bounds__(512) void bucketspmm_kernel(const uint2* __restrict__ erec,
                                                         const unsigned* __restrict__ offsets,
                                                         const unsigned* __restrict__ counts,
                                                         const unsigned short* __restrict__ Hc,
                                                         float* __restrict__ out, int N) {
    __shared__ float acc[RPB * 65];
    const int t = threadIdx.x;
    for (int i = t; i < RPB * 65; i += 512) acc[i] = 0.0f;
    __syncthreads();

    const int bucket = blockIdx.x;
    const unsigned start = offsets[bucket];
    const unsigned cnt   = counts[bucket];
    const int sub = t & 15;            // 16 lanes per edge

    for (unsigned i = 0; i < cnt; i += 32) {
        const unsigned idx = i + (unsigned)(t >> 4);
        if (idx < cnt) {
            const uint2 rec = erec[start + idx];
            const unsigned col = rec.x & 0xffffu;
            const unsigned rib = rec.x >> 16;
            const float w0 = bf_lo(rec.y);
            const float w1 = bf_hi(rec.y);
            const uint2* hp = reinterpret_cast<const uint2*>(Hc + (size_t)col * COLS);
            const uint2 h0 = hp[sub];
            const uint2 h1 = hp[16 + sub];
            float* ap = &acc[rib * 65 + sub * 4];
            atomicAdd(ap + 0, w0 * bf_lo(h0.x) + w1 * bf_lo(h1.x));
            atomicAdd(ap + 1, w0 * bf_hi(h0.x) + w1 * bf_hi(h1.x));
            atomicAdd(ap + 2, w0 * bf_lo(h0.y) + w1 * bf_lo(h1.y));
            atomicAdd(ap + 3, w0 * bf_hi(h0.y) + w1 * bf_hi(h1.y));
        }
    }
    __syncthreads();

    const int dim = t & 63;
    const int rg  = t >> 6;            // 0..7
    const int row0 = bucket * RPB;
    #pragma unroll
    for (int rr = 0; rr < 8; ++rr) {
        const int r = rg * 8 + rr;
        const int row = row0 + r;
        if (row < N) out[(size_t)row * D_OUT + dim] = acc[r * 65 + dim];
    }
}

// ---------------------------------------------------------------------------
extern "C" void kernel_launch(void* const* d_in, const int* in_sizes, int n_in,
                              void* d_out, int out_size, void* d_ws, size_t ws_size,
                              hipStream_t stream) {
    const float* H    = (const float*)d_in[0];  // [N,128]
    const float* vals = (const float*)d_in[1];  // [4,E]
    const float* W    = (const float*)d_in[2];  // [2,128,64]
    const float* att  = (const float*)d_in[3];  // [2,128,4]
    const int*   rows = (const int*)d_in[4];    // [4,E]
    const int*   cols = (const int*)d_in[5];    // [4,E]

    const int N    = in_sizes[0] / D_IN;        // 50000
    const int TE   = in_sizes[1];               // 3.2M
    const int Eper = TE / NUM_A;                // 800000
    const int NB   = (N + RPB - 1) / RPB;       // 782

    char* ws = (char*)d_ws;
    size_t off = 0;
    float* ws_score = (float*)(ws + off);          off += 256;
    unsigned short* ws_Hc = (unsigned short*)(ws + off);
    off += (size_t)N * COLS * sizeof(unsigned short);
    off = (off + 255) & ~(size_t)255;
    unsigned* counts  = (unsigned*)(ws + off);     off += (size_t)MAXNB * sizeof(unsigned);
    unsigned* offsets = (unsigned*)(ws + off);     off += (size_t)MAXNB * sizeof(unsigned);
    unsigned* cursor  = (unsigned*)(ws + off);     off += (size_t)MAXNB * sizeof(unsigned);
    off = (off + 255) & ~(size_t)255;
    uint2* erec       = (uint2*)(ws + off);        off += (size_t)TE * sizeof(uint2);

    hipMemsetAsync(counts, 0, (size_t)NB * sizeof(unsigned), stream);

    score_kernel<<<1, 64, 0, stream>>>(att, ws_score);

    gemm_kernel<<<(N + 31) / 32, 256, 0, stream>>>(H, W, ws_Hc, N);

    hist_kernel<<<512, 1024, 0, stream>>>(rows, counts, TE, NB);
    scan_kernel<<<1, 1024, 0, stream>>>(counts, offsets, cursor, NB);

    const int sblocks = (TE + SC_CH - 1) / SC_CH;
    scatter_kernel<<<sblocks, SC_T, 0, stream>>>(rows, cols, vals, ws_score,
                                                 cursor, erec, TE, Eper, NB);

    bucketspmm_kernel<<<NB, 512, 0, stream>>>(erec, offsets, counts, ws_Hc,
                                              (float*)d_out, N);
}

// Round 4
// 401.620 us; speedup vs baseline: 3.7992x; 3.7992x over previous
//
#include <hip/hip_runtime.h>

// Problem constants (fixed by the reference file)
constexpr int D_IN  = 128;
constexpr int D_OUT = 64;
constexpr int NCH   = 2;
constexpr int NUM_A = 4;
constexpr int COLS  = NCH * D_OUT;     // 128 bf16 per Hc row (ch0 64 | ch1 64)
constexpr int RPB   = 64;              // rows per bucket
constexpr int MAXNB = 800;             // LDS cap (N up to 51200)
constexpr int HPAD  = 130;             // gemm LDS row stride (breaks bank conflicts)
constexpr int CAP   = 4608;            // sorted-record LDS capacity per chunk
constexpr int SPT   = 512;             // spmm block threads
constexpr int RPT   = CAP / SPT;       // 9 records held per thread

__device__ inline unsigned short f2bf_rn(float f) {
    unsigned u = __float_as_uint(f);
    return (unsigned short)((u + 0x7fffu + ((u >> 16) & 1u)) >> 16);
}

// ---------------------------------------------------------------------------
// Kernel 1: score[c][a] = 0.5 * softmax_a( mean_d att[c][d][a] )
// ---------------------------------------------------------------------------
__global__ __launch_bounds__(64) void score_kernel(const float* __restrict__ att,
                                                   float* __restrict__ score) {
    int lane = threadIdx.x;
    int c = lane >> 2, a = lane & 3;
    float s = 0.0f;
    if (lane < 8) {
        const float* p = att + c * (D_IN * NUM_A) + a;
        for (int d = 0; d < D_IN; ++d) s += p[d * NUM_A];
        s *= (1.0f / D_IN);
    }
    float m = fmaxf(s, __shfl_xor(s, 1));
    m = fmaxf(m, __shfl_xor(m, 2));
    float ex = __expf(s - m);
    float sum = ex + __shfl_xor(ex, 1);
    sum += __shfl_xor(sum, 2);
    if (lane < 8) score[lane] = 0.5f * ex / sum;   // fold the channel-mean 0.5 in
}

// ---------------------------------------------------------------------------
// Kernel 2: Hc[n][c*64+o] = sum_k H[n][k]*W[c][k][o], output bf16
// ---------------------------------------------------------------------------
__global__ __launch_bounds__(256) void gemm_kernel(const float* __restrict__ H,
                                                   const float* __restrict__ W,
                                                   unsigned short* __restrict__ Hc, int N) {
    __shared__ float Hs[32 * HPAD];          // stride 130 breaks bank conflicts
    const int t    = threadIdx.x;
    const int row0 = blockIdx.x * 32;
    const int nvalid = min(32, N - row0);

    const float4* src = reinterpret_cast<const float4*>(H + (size_t)row0 * D_IN);
    for (int i = t; i < nvalid * 32; i += 256) {
        const int r = i >> 5, q = i & 31;
        float4 v = src[(size_t)r * 32 + q];
        float2* d = reinterpret_cast<float2*>(&Hs[r * HPAD + q * 4]);
        d[0] = make_float2(v.x, v.y);
        d[1] = make_float2(v.z, v.w);
    }
    __syncthreads();

    const int pair = t & 63;
    const int rg   = t >> 6;
    const int co0  = pair * 2;
    const int c    = co0 >> 6;
    const int o    = co0 & 63;

    const float* Wp = W + c * (D_IN * D_OUT) + o;
    const float* hs = Hs + rg * 8 * HPAD;

    float acc[8][2];
    #pragma unroll
    for (int r = 0; r < 8; ++r) { acc[r][0] = 0.f; acc[r][1] = 0.f; }

    #pragma unroll 4
    for (int k = 0; k < D_IN; ++k) {
        const float2 w = *reinterpret_cast<const float2*>(Wp + k * D_OUT);
        #pragma unroll
        for (int r = 0; r < 8; ++r) {
            const float h = hs[r * HPAD + k];
            acc[r][0] += h * w.x;
            acc[r][1] += h * w.y;
        }
    }

    #pragma unroll
    for (int r = 0; r < 8; ++r) {
        const int row = row0 + rg * 8 + r;
        if (row < N) {
            unsigned pk = (unsigned)f2bf_rn(acc[r][0]) | ((unsigned)f2bf_rn(acc[r][1]) << 16);
            *reinterpret_cast<unsigned*>(Hc + (size_t)row * COLS + co0) = pk;
        }
    }
}

// ---------------------------------------------------------------------------
// Kernel 3: LDS-aggregated histogram of buckets (bucket = row >> 6)
// ---------------------------------------------------------------------------
__global__ __launch_bounds__(1024) void hist_kernel(const int* __restrict__ rows,
                                                    unsigned* __restrict__ counts,
                                                    int TE, int NB) {
    __shared__ unsigned h[MAXNB];
    const int t = threadIdx.x;
    for (int i = t; i < MAXNB; i += 1024) h[i] = 0u;
    __syncthreads();
    for (int e = blockIdx.x * 1024 + t; e < TE; e += gridDim.x * 1024)
        atomicAdd(&h[rows[e] >> 6], 1u);
    __syncthreads();
    for (int i = t; i < NB; i += 1024)
        if (h[i]) atomicAdd(&counts[i], h[i]);
}

// ---------------------------------------------------------------------------
// Kernel 4: exclusive scan of counts -> offsets (and cursor copy). 1 block.
// ---------------------------------------------------------------------------
__global__ __launch_bounds__(1024) void scan_kernel(const unsigned* __restrict__ counts,
                                                    unsigned* __restrict__ offsets,
                                                    unsigned* __restrict__ cursor, int n) {
    __shared__ unsigned part[1024];
    const int t = threadIdx.x;
    const int chunk = (n + 1023) >> 10;
    const int s = t * chunk;
    const int e = min(s + chunk, n);
    unsigned sum = 0;
    for (int i = s; i < e; ++i) sum += counts[i];
    part[t] = sum;
    __syncthreads();
    for (int d = 1; d < 1024; d <<= 1) {
        unsigned v = (t >= d) ? part[t - d] : 0u;
        __syncthreads();
        part[t] += v;
        __syncthreads();
    }
    unsigned run = (t == 0) ? 0u : part[t - 1];
    for (int i = s; i < e; ++i) {
        const unsigned c = counts[i];
        offsets[i] = run;
        cursor[i]  = run;
        run += c;
    }
}

// ---------------------------------------------------------------------------
// Kernel 5: LDS-aggregated scatter into bucket-major records.
// record.x = col | (row_in_bucket << 16); record.y = bf16(w0) | bf16(w1)<<16
// ---------------------------------------------------------------------------
constexpr int SC_T   = 512;
constexpr int SC_EPT = 8;
constexpr int SC_CH  = SC_T * SC_EPT;   // 4096 edges per block

__global__ __launch_bounds__(SC_T) void scatter_kernel(const int* __restrict__ rows,
                                                       const int* __restrict__ cols,
                                                       const float* __restrict__ vals,
                                                       const float* __restrict__ score,
                                                       unsigned* __restrict__ cursor,
                                                       uint2* __restrict__ erec,
                                                       int TE, int Eper, int NB) {
    __shared__ unsigned lh[MAXNB];     // local hist, then local cursor
    __shared__ unsigned base[MAXNB];   // claimed global base
    const int t  = threadIdx.x;
    const int e0 = blockIdx.x * SC_CH;

    for (int i = t; i < MAXNB; i += SC_T) lh[i] = 0u;
    __syncthreads();

    int   rw[SC_EPT]; int cl[SC_EPT]; float w0[SC_EPT], w1[SC_EPT];
    #pragma unroll
    for (int k = 0; k < SC_EPT; ++k) {
        const int e = e0 + k * SC_T + t;
        rw[k] = -1;
        if (e < TE) {
            rw[k] = rows[e];
            cl[k] = cols[e];
            const float v = vals[e];
            const int  a = e / Eper;
            w0[k] = score[a] * v;
            w1[k] = score[4 + a] * v;
            atomicAdd(&lh[rw[k] >> 6], 1u);
        }
    }
    __syncthreads();

    for (int i = t; i < NB; i += SC_T) {
        const unsigned c = lh[i];
        base[i] = c ? atomicAdd(&cursor[i], c) : 0u;
        lh[i] = 0u;                    // reuse as local cursor
    }
    __syncthreads();

    #pragma unroll
    for (int k = 0; k < SC_EPT; ++k) {
        if (rw[k] >= 0) {
            const int b   = rw[k] >> 6;
            const unsigned rank = atomicAdd(&lh[b], 1u);
            const unsigned pos  = base[b] + rank;
            const unsigned meta = (unsigned)cl[k] | ((unsigned)(rw[k] & 63) << 16);
            const unsigned wpk  = (unsigned)f2bf_rn(w0[k]) | ((unsigned)f2bf_rn(w1[k]) << 16);
            erec[pos] = make_uint2(meta, wpk);
        }
    }
}

// ---------------------------------------------------------------------------
// Kernel 6: bucket-SpMM, atomic-free accumulation.
// Per chunk: counting-sort bucket records by row-in-bucket into LDS (integer
// LDS atomics only), then wave w accumulates rows w*8..w*8+7 in REGISTERS:
// all 64 lanes broadcast-read each record; lane l reads Hc32[col*64 + l]
// (one uint = 2 bf16 dims; lanes<32 -> ch0 dims, lanes>=32 -> ch1 dims);
// lanes<32 weight by w0, lanes>=32 by w1; shfl_xor(32) combines channels.
// ---------------------------------------------------------------------------
__global__ __launch_bounds__(SPT) void bucketspmm_kernel(const uint2* __restrict__ erec,
                                                         const unsigned* __restrict__ offsets,
                                                         const unsigned* __restrict__ counts,
                                                         const unsigned* __restrict__ Hc32,
                                                         float* __restrict__ out, int N) {
    __shared__ __align__(16) uint2 srec[CAP];   // 36.9 KB sorted records
    __shared__ unsigned roff[RPB + 1];
    __shared__ unsigned rcur[RPB];

    const int t    = threadIdx.x;
    const int lane = t & 63;
    const int w    = t >> 6;                    // wave 0..7
    const int bucket = blockIdx.x;
    const unsigned start = offsets[bucket];
    const unsigned cnt   = counts[bucket];
    const int wsh = (lane < 32) ? 16 : 0;       // bf16 weight select per lane half

    float2 acc[8];
    #pragma unroll
    for (int r = 0; r < 8; ++r) acc[r] = make_float2(0.f, 0.f);

    for (unsigned cb = 0; cb < cnt; cb += CAP) {
        const unsigned cn = min(cnt - cb, (unsigned)CAP);

        if (t < RPB) roff[t] = 0u;
        __syncthreads();

        // load records into registers + histogram rib
        uint2 rec[RPT];
        #pragma unroll
        for (int k = 0; k < RPT; ++k) {
            const unsigned idx = (unsigned)(k * SPT + t);
            rec[k] = make_uint2(0xffffffffu, 0u);
            if (idx < cn) {
                rec[k] = erec[start + cb + idx];
                atomicAdd(&roff[rec[k].x >> 16], 1u);
            }
        }
        __syncthreads();

        // exclusive scan of 64 counts by wave 0
        if (t < 64) {
            const unsigned v = roff[t];
            unsigned incl = v;
            #pragma unroll
            for (int d = 1; d < 64; d <<= 1) {
                const unsigned nb = __shfl_up(incl, d);
                if (lane >= d) incl += nb;
            }
            const unsigned excl = incl - v;
            roff[t] = excl;
            rcur[t] = excl;
            if (t == 0) roff[RPB] = cn;
        }
        __syncthreads();

        // scatter records into row-sorted LDS order
        #pragma unroll
        for (int k = 0; k < RPT; ++k) {
            if (rec[k].x != 0xffffffffu) {
                const unsigned rib = rec[k].x >> 16;
                const unsigned pos = atomicAdd(&rcur[rib], 1u);
                srec[pos] = make_uint2(rec[k].x & 0xffffu, rec[k].y);
            }
        }
        __syncthreads();

        // register-accumulating SpMM over this chunk
        #pragma unroll
        for (int rr = 0; rr < 8; ++rr) {
            const int r = w * 8 + rr;
            unsigned j = roff[r];
            const unsigned e = roff[r + 1];
            float2 a = acc[rr];
            if ((j & 1u) && j < e) {
                const uint2 rc = srec[j];
                const unsigned hv = Hc32[(rc.x << 6) + lane];
                const float wv = __uint_as_float((rc.y << wsh) & 0xffff0000u);
                a.x += wv * __uint_as_float(hv << 16);
                a.y += wv * __uint_as_float(hv & 0xffff0000u);
                ++j;
            }
            for (; j + 1 < e; j += 2) {
                const uint4 two = *reinterpret_cast<const uint4*>(&srec[j]);
                const unsigned hv0 = Hc32[(two.x << 6) + lane];
                const unsigned hv1 = Hc32[(two.z << 6) + lane];
                const float wv0 = __uint_as_float((two.y << wsh) & 0xffff0000u);
                const float wv1 = __uint_as_float((two.w << wsh) & 0xffff0000u);
                a.x += wv0 * __uint_as_float(hv0 << 16);
                a.y += wv0 * __uint_as_float(hv0 & 0xffff0000u);
                a.x += wv1 * __uint_as_float(hv1 << 16);
                a.y += wv1 * __uint_as_float(hv1 & 0xffff0000u);
            }
            if (j < e) {
                const uint2 rc = srec[j];
                const unsigned hv = Hc32[(rc.x << 6) + lane];
                const float wv = __uint_as_float((rc.y << wsh) & 0xffff0000u);
                a.x += wv * __uint_as_float(hv << 16);
                a.y += wv * __uint_as_float(hv & 0xffff0000u);
            }
            acc[rr] = a;
        }
        __syncthreads();
    }

    // combine channel halves and store (covers zero rows too)
    const int row0 = bucket * RPB + w * 8;
    #pragma unroll
    for (int rr = 0; rr < 8; ++rr) {
        float2 a = acc[rr];
        a.x += __shfl_xor(a.x, 32);
        a.y += __shfl_xor(a.y, 32);
        const int row = row0 + rr;
        if (lane < 32 && row < N) {
            *reinterpret_cast<float2*>(out + (size_t)row * D_OUT + lane * 2) = a;
        }
    }
}

// ---------------------------------------------------------------------------
extern "C" void kernel_launch(void* const* d_in, const int* in_sizes, int n_in,
                              void* d_out, int out_size, void* d_ws, size_t ws_size,
                              hipStream_t stream) {
    const float* H    = (const float*)d_in[0];  // [N,128]
    const float* vals = (const float*)d_in[1];  // [4,E]
    const float* W    = (const float*)d_in[2];  // [2,128,64]
    const float* att  = (const float*)d_in[3];  // [2,128,4]
    const int*   rows = (const int*)d_in[4];    // [4,E]
    const int*   cols = (const int*)d_in[5];    // [4,E]

    const int N    = in_sizes[0] / D_IN;        // 50000
    const int TE   = in_sizes[1];               // 3.2M
    const int Eper = TE / NUM_A;                // 800000
    const int NB   = (N + RPB - 1) / RPB;       // 782

    char* ws = (char*)d_ws;
    size_t off = 0;
    float* ws_score = (float*)(ws + off);          off += 256;
    unsigned short* ws_Hc = (unsigned short*)(ws + off);
    off += (size_t)N * COLS * sizeof(unsigned short);
    off = (off + 255) & ~(size_t)255;
    unsigned* counts  = (unsigned*)(ws + off);     off += (size_t)MAXNB * sizeof(unsigned);
    unsigned* offsets = (unsigned*)(ws + off);     off += (size_t)MAXNB * sizeof(unsigned);
    unsigned* cursor  = (unsigned*)(ws + off);     off += (size_t)MAXNB * sizeof(unsigned);
    off = (off + 255) & ~(size_t)255;
    uint2* erec       = (uint2*)(ws + off);        off += (size_t)TE * sizeof(uint2);

    hipMemsetAsync(counts, 0, (size_t)NB * sizeof(unsigned), stream);

    score_kernel<<<1, 64, 0, stream>>>(att, ws_score);

    gemm_kernel<<<(N + 31) / 32, 256, 0, stream>>>(H, W, ws_Hc, N);

    hist_kernel<<<512, 1024, 0, stream>>>(rows, counts, TE, NB);
    scan_kernel<<<1, 1024, 0, stream>>>(counts, offsets, cursor, NB);

    const int sblocks = (TE + SC_CH - 1) / SC_CH;
    scatter_kernel<<<sblocks, SC_T, 0, stream>>>(rows, cols, vals, ws_score,
                                                 cursor, erec, TE, Eper, NB);

    bucketspmm_kernel<<<NB, SPT, 0, stream>>>(erec, offsets, counts,
                                              (const unsigned*)ws_Hc,
                                              (float*)d_out, N);
}

// Round 5
// 298.934 us; speedup vs baseline: 5.1043x; 1.3435x over previous
//
#include <hip/hip_runtime.h>

// Problem constants (fixed by the reference file)
constexpr int D_IN  = 128;
constexpr int D_OUT = 64;
constexpr int NCH   = 2;
constexpr int NUM_A = 4;
constexpr int COLS  = NCH * D_OUT;     // 128 bf16 per Hc row (ch0 64 | ch1 64)
constexpr int RPB   = 64;              // rows per bucket
constexpr int MAXNB = 800;             // LDS cap (N up to 51200)
constexpr int HPAD  = 130;             // gemm LDS row stride (breaks bank conflicts)
constexpr int CAP   = 4608;            // sorted-record LDS capacity per chunk
constexpr int SPT   = 512;             // spmm block threads
constexpr int RPT   = CAP / SPT;       // 9 records held per thread

__device__ inline unsigned short f2bf_rn(float f) {
    unsigned u = __float_as_uint(f);
    return (unsigned short)((u + 0x7fffu + ((u >> 16) & 1u)) >> 16);
}

// ---------------------------------------------------------------------------
// Kernel 1: score[c][a] = 0.5 * softmax_a( mean_d att[c][d][a] )
// ---------------------------------------------------------------------------
__global__ __launch_bounds__(64) void score_kernel(const float* __restrict__ att,
                                                   float* __restrict__ score) {
    int lane = threadIdx.x;
    int c = lane >> 2, a = lane & 3;
    float s = 0.0f;
    if (lane < 8) {
        const float* p = att + c * (D_IN * NUM_A) + a;
        for (int d = 0; d < D_IN; ++d) s += p[d * NUM_A];
        s *= (1.0f / D_IN);
    }
    float m = fmaxf(s, __shfl_xor(s, 1));
    m = fmaxf(m, __shfl_xor(m, 2));
    float ex = __expf(s - m);
    float sum = ex + __shfl_xor(ex, 1);
    sum += __shfl_xor(sum, 2);
    if (lane < 8) score[lane] = 0.5f * ex / sum;   // fold the channel-mean 0.5 in
}

// ---------------------------------------------------------------------------
// Kernel 2: Hc[n][c*64+o] = sum_k H[n][k]*W[c][k][o], output bf16
// ---------------------------------------------------------------------------
__global__ __launch_bounds__(256) void gemm_kernel(const float* __restrict__ H,
                                                   const float* __restrict__ W,
                                                   unsigned short* __restrict__ Hc, int N) {
    __shared__ float Hs[32 * HPAD];          // stride 130 breaks bank conflicts
    const int t    = threadIdx.x;
    const int row0 = blockIdx.x * 32;
    const int nvalid = min(32, N - row0);

    const float4* src = reinterpret_cast<const float4*>(H + (size_t)row0 * D_IN);
    for (int i = t; i < nvalid * 32; i += 256) {
        const int r = i >> 5, q = i & 31;
        float4 v = src[(size_t)r * 32 + q];
        float2* d = reinterpret_cast<float2*>(&Hs[r * HPAD + q * 4]);
        d[0] = make_float2(v.x, v.y);
        d[1] = make_float2(v.z, v.w);
    }
    __syncthreads();

    const int pair = t & 63;
    const int rg   = t >> 6;
    const int co0  = pair * 2;
    const int c    = co0 >> 6;
    const int o    = co0 & 63;

    const float* Wp = W + c * (D_IN * D_OUT) + o;
    const float* hs = Hs + rg * 8 * HPAD;

    float acc[8][2];
    #pragma unroll
    for (int r = 0; r < 8; ++r) { acc[r][0] = 0.f; acc[r][1] = 0.f; }

    #pragma unroll 4
    for (int k = 0; k < D_IN; ++k) {
        const float2 w = *reinterpret_cast<const float2*>(Wp + k * D_OUT);
        #pragma unroll
        for (int r = 0; r < 8; ++r) {
            const float h = hs[r * HPAD + k];
            acc[r][0] += h * w.x;
            acc[r][1] += h * w.y;
        }
    }

    #pragma unroll
    for (int r = 0; r < 8; ++r) {
        const int row = row0 + rg * 8 + r;
        if (row < N) {
            unsigned pk = (unsigned)f2bf_rn(acc[r][0]) | ((unsigned)f2bf_rn(acc[r][1]) << 16);
            *reinterpret_cast<unsigned*>(Hc + (size_t)row * COLS + co0) = pk;
        }
    }
}

// ---------------------------------------------------------------------------
// Kernel 3: LDS-aggregated histogram of buckets (bucket = row >> 6)
// ---------------------------------------------------------------------------
__global__ __launch_bounds__(1024) void hist_kernel(const int* __restrict__ rows,
                                                    unsigned* __restrict__ counts,
                                                    int TE, int NB) {
    __shared__ unsigned h[MAXNB];
    const int t = threadIdx.x;
    for (int i = t; i < MAXNB; i += 1024) h[i] = 0u;
    __syncthreads();
    for (int e = blockIdx.x * 1024 + t; e < TE; e += gridDim.x * 1024)
        atomicAdd(&h[rows[e] >> 6], 1u);
    __syncthreads();
    for (int i = t; i < NB; i += 1024)
        if (h[i]) atomicAdd(&counts[i], h[i]);
}

// ---------------------------------------------------------------------------
// Kernel 4: exclusive scan of counts -> offsets (and cursor copy). 1 block.
// ---------------------------------------------------------------------------
__global__ __launch_bounds__(1024) void scan_kernel(const unsigned* __restrict__ counts,
                                                    unsigned* __restrict__ offsets,
                                                    unsigned* __restrict__ cursor, int n) {
    __shared__ unsigned part[1024];
    const int t = threadIdx.x;
    const int chunk = (n + 1023) >> 10;
    const int s = t * chunk;
    const int e = min(s + chunk, n);
    unsigned sum = 0;
    for (int i = s; i < e; ++i) sum += counts[i];
    part[t] = sum;
    __syncthreads();
    for (int d = 1; d < 1024; d <<= 1) {
        unsigned v = (t >= d) ? part[t - d] : 0u;
        __syncthreads();
        part[t] += v;
        __syncthreads();
    }
    unsigned run = (t == 0) ? 0u : part[t - 1];
    for (int i = s; i < e; ++i) {
        const unsigned c = counts[i];
        offsets[i] = run;
        cursor[i]  = run;
        run += c;
    }
}

// ---------------------------------------------------------------------------
// Kernel 5: LDS-aggregated scatter into bucket-major records.
// record.x = col | (row_in_bucket << 16); record.y = bf16(w0) | bf16(w1)<<16
// 1024 threads x 8 edges = 8192 edges/block (halves cursor contention).
// ---------------------------------------------------------------------------
constexpr int SC_T   = 1024;
constexpr int SC_EPT = 8;
constexpr int SC_CH  = SC_T * SC_EPT;   // 8192 edges per block

__global__ __launch_bounds__(SC_T) void scatter_kernel(const int* __restrict__ rows,
                                                       const int* __restrict__ cols,
                                                       const float* __restrict__ vals,
                                                       const float* __restrict__ score,
                                                       unsigned* __restrict__ cursor,
                                                       uint2* __restrict__ erec,
                                                       int TE, int Eper, int NB) {
    __shared__ unsigned lh[MAXNB];     // local hist, then local cursor
    __shared__ unsigned base[MAXNB];   // claimed global base
    const int t  = threadIdx.x;
    const int e0 = blockIdx.x * SC_CH;

    for (int i = t; i < MAXNB; i += SC_T) lh[i] = 0u;
    __syncthreads();

    int   rw[SC_EPT]; int cl[SC_EPT]; float w0[SC_EPT], w1[SC_EPT];
    #pragma unroll
    for (int k = 0; k < SC_EPT; ++k) {
        const int e = e0 + k * SC_T + t;
        rw[k] = -1;
        if (e < TE) {
            rw[k] = rows[e];
            cl[k] = cols[e];
            const float v = vals[e];
            const int  a = e / Eper;
            w0[k] = score[a] * v;
            w1[k] = score[4 + a] * v;
            atomicAdd(&lh[rw[k] >> 6], 1u);
        }
    }
    __syncthreads();

    for (int i = t; i < NB; i += SC_T) {
        const unsigned c = lh[i];
        base[i] = c ? atomicAdd(&cursor[i], c) : 0u;
        lh[i] = 0u;                    // reuse as local cursor
    }
    __syncthreads();

    #pragma unroll
    for (int k = 0; k < SC_EPT; ++k) {
        if (rw[k] >= 0) {
            const int b   = rw[k] >> 6;
            const unsigned rank = atomicAdd(&lh[b], 1u);
            const unsigned pos  = base[b] + rank;
            const unsigned meta = (unsigned)cl[k] | ((unsigned)(rw[k] & 63) << 16);
            const unsigned wpk  = (unsigned)f2bf_rn(w0[k]) | ((unsigned)f2bf_rn(w1[k]) << 16);
            erec[pos] = make_uint2(meta, wpk);
        }
    }
}

// ---------------------------------------------------------------------------
// Kernel 6: bucket-SpMM, atomic-free register accumulation, 8-deep MLP.
// Per chunk: counting-sort records by row-in-bucket into LDS; wave w owns
// rows w*8..w*8+7; inner loop batches 8 records: 8 broadcast LDS reads,
// 8 independent coalesced Hc gathers in flight, then 16 FMAs.
// ---------------------------------------------------------------------------
__global__ __launch_bounds__(SPT) void bucketspmm_kernel(const uint2* __restrict__ erec,
                                                         const unsigned* __restrict__ offsets,
                                                         const unsigned* __restrict__ counts,
                                                         const unsigned* __restrict__ Hc32,
                                                         float* __restrict__ out, int N) {
    __shared__ __align__(16) uint2 srec[CAP];   // 36.9 KB sorted records
    __shared__ unsigned roff[RPB + 1];
    __shared__ unsigned rcur[RPB];

    const int t    = threadIdx.x;
    const int lane = t & 63;
    const int w    = t >> 6;                    // wave 0..7
    const int bucket = blockIdx.x;
    const unsigned start = offsets[bucket];
    const unsigned cnt   = counts[bucket];
    const int wsh = (lane < 32) ? 16 : 0;       // bf16 weight select per lane half

    float2 acc[8];
    #pragma unroll
    for (int r = 0; r < 8; ++r) acc[r] = make_float2(0.f, 0.f);

    for (unsigned cb = 0; cb < cnt; cb += CAP) {
        const unsigned cn = min(cnt - cb, (unsigned)CAP);

        if (t < RPB) roff[t] = 0u;
        __syncthreads();

        // load records into registers + histogram rib
        uint2 rec[RPT];
        #pragma unroll
        for (int k = 0; k < RPT; ++k) {
            const unsigned idx = (unsigned)(k * SPT + t);
            rec[k] = make_uint2(0xffffffffu, 0u);
            if (idx < cn) {
                rec[k] = erec[start + cb + idx];
                atomicAdd(&roff[rec[k].x >> 16], 1u);
            }
        }
        __syncthreads();

        // exclusive scan of 64 counts by wave 0
        if (t < 64) {
            const unsigned v = roff[t];
            unsigned incl = v;
            #pragma unroll
            for (int d = 1; d < 64; d <<= 1) {
                const unsigned nb = __shfl_up(incl, d);
                if (lane >= d) incl += nb;
            }
            const unsigned excl = incl - v;
            roff[t] = excl;
            rcur[t] = excl;
            if (t == 0) roff[RPB] = cn;
        }
        __syncthreads();

        // scatter records into row-sorted LDS order
        #pragma unroll
        for (int k = 0; k < RPT; ++k) {
            if (rec[k].x != 0xffffffffu) {
                const unsigned rib = rec[k].x >> 16;
                const unsigned pos = atomicAdd(&rcur[rib], 1u);
                srec[pos] = make_uint2(rec[k].x & 0xffffu, rec[k].y);
            }
        }
        __syncthreads();

        // register-accumulating SpMM over this chunk, 8 records in flight
        #pragma unroll
        for (int rr = 0; rr < 8; ++rr) {
            const int r = w * 8 + rr;
            unsigned j = roff[r];
            const unsigned e = roff[r + 1];
            float2 a = acc[rr];

            while (j + 8 <= e) {
                float    wv8[8];
                unsigned hv8[8];
                #pragma unroll
                for (int k = 0; k < 8; ++k) {
                    const uint2 rc = srec[j + k];
                    hv8[k] = Hc32[(rc.x << 6) + lane];
                    wv8[k] = __uint_as_float((rc.y << wsh) & 0xffff0000u);
                }
                #pragma unroll
                for (int k = 0; k < 8; ++k) {
                    a.x += wv8[k] * __uint_as_float(hv8[k] << 16);
                    a.y += wv8[k] * __uint_as_float(hv8[k] & 0xffff0000u);
                }
                j += 8;
            }
            for (; j < e; ++j) {
                const uint2 rc = srec[j];
                const unsigned hv = Hc32[(rc.x << 6) + lane];
                const float wv = __uint_as_float((rc.y << wsh) & 0xffff0000u);
                a.x += wv * __uint_as_float(hv << 16);
                a.y += wv * __uint_as_float(hv & 0xffff0000u);
            }
            acc[rr] = a;
        }
        __syncthreads();
    }

    // combine channel halves and store (covers zero rows too)
    const int row0 = bucket * RPB + w * 8;
    #pragma unroll
    for (int rr = 0; rr < 8; ++rr) {
        float2 a = acc[rr];
        a.x += __shfl_xor(a.x, 32);
        a.y += __shfl_xor(a.y, 32);
        const int row = row0 + rr;
        if (lane < 32 && row < N) {
            *reinterpret_cast<float2*>(out + (size_t)row * D_OUT + lane * 2) = a;
        }
    }
}

// ---------------------------------------------------------------------------
extern "C" void kernel_launch(void* const* d_in, const int* in_sizes, int n_in,
                              void* d_out, int out_size, void* d_ws, size_t ws_size,
                              hipStream_t stream) {
    const float* H    = (const float*)d_in[0];  // [N,128]
    const float* vals = (const float*)d_in[1];  // [4,E]
    const float* W    = (const float*)d_in[2];  // [2,128,64]
    const float* att  = (const float*)d_in[3];  // [2,128,4]
    const int*   rows = (const int*)d_in[4];    // [4,E]
    const int*   cols = (const int*)d_in[5];    // [4,E]

    const int N    = in_sizes[0] / D_IN;        // 50000
    const int TE   = in_sizes[1];               // 3.2M
    const int Eper = TE / NUM_A;                // 800000
    const int NB   = (N + RPB - 1) / RPB;       // 782

    char* ws = (char*)d_ws;
    size_t off = 0;
    float* ws_score = (float*)(ws + off);          off += 256;
    unsigned short* ws_Hc = (unsigned short*)(ws + off);
    off += (size_t)N * COLS * sizeof(unsigned short);
    off = (off + 255) & ~(size_t)255;
    unsigned* counts  = (unsigned*)(ws + off);     off += (size_t)MAXNB * sizeof(unsigned);
    unsigned* offsets = (unsigned*)(ws + off);     off += (size_t)MAXNB * sizeof(unsigned);
    unsigned* cursor  = (unsigned*)(ws + off);     off += (size_t)MAXNB * sizeof(unsigned);
    off = (off + 255) & ~(size_t)255;
    uint2* erec       = (uint2*)(ws + off);        off += (size_t)TE * sizeof(uint2);

    hipMemsetAsync(counts, 0, (size_t)NB * sizeof(unsigned), stream);

    score_kernel<<<1, 64, 0, stream>>>(att, ws_score);

    gemm_kernel<<<(N + 31) / 32, 256, 0, stream>>>(H, W, ws_Hc, N);

    hist_kernel<<<512, 1024, 0, stream>>>(rows, counts, TE, NB);
    scan_kernel<<<1, 1024, 0, stream>>>(counts, offsets, cursor, NB);

    const int sblocks = (TE + SC_CH - 1) / SC_CH;
    scatter_kernel<<<sblocks, SC_T, 0, stream>>>(rows, cols, vals, ws_score,
                                                 cursor, erec, TE, Eper, NB);

    bucketspmm_kernel<<<NB, SPT, 0, stream>>>(erec, offsets, counts,
                                              (const unsigned*)ws_Hc,
                                              (float*)d_out, N);
}

// Round 6
// 278.140 us; speedup vs baseline: 5.4859x; 1.0748x over previous
//
#include <hip/hip_runtime.h>

// Problem constants (fixed by the reference file)
constexpr int D_IN  = 128;
constexpr int D_OUT = 64;
constexpr int NCH   = 2;
constexpr int NUM_A = 4;
constexpr int COLS  = NCH * D_OUT;     // 128 bf16 per Hc row (ch0 64 | ch1 64)
constexpr int RPB   = 64;              // rows per bucket
constexpr int MAXNB = 800;             // LDS cap (N up to 51200)
constexpr int CAP   = 4608;            // spmm sorted-record LDS capacity per chunk
constexpr int SPT   = 512;             // spmm block threads
constexpr int RPT   = CAP / SPT;       // 9 records held per thread

typedef __attribute__((ext_vector_type(8))) short bf16x8;   // 8 bf16 in 4 VGPRs
typedef __attribute__((ext_vector_type(4))) float f32x4;

__device__ inline unsigned short f2bf_rn(float f) {
    unsigned u = __float_as_uint(f);
    return (unsigned short)((u + 0x7fffu + ((u >> 16) & 1u)) >> 16);
}

// ---------------------------------------------------------------------------
// Kernel 1: score[c][a] = 0.5 * softmax_a( mean_d att[c][d][a] )
// Also zero-inits the bucket counters (replaces a memset launch).
// ---------------------------------------------------------------------------
__global__ __launch_bounds__(64) void score_kernel(const float* __restrict__ att,
                                                   float* __restrict__ score,
                                                   unsigned* __restrict__ counts, int NB) {
    int lane = threadIdx.x;
    for (int i = lane; i < NB; i += 64) counts[i] = 0u;
    int c = lane >> 2, a = lane & 3;
    float s = 0.0f;
    if (lane < 8) {
        const float* p = att + c * (D_IN * NUM_A) + a;
        for (int d = 0; d < D_IN; ++d) s += p[d * NUM_A];
        s *= (1.0f / D_IN);
    }
    float m = fmaxf(s, __shfl_xor(s, 1));
    m = fmaxf(m, __shfl_xor(m, 2));
    float ex = __expf(s - m);
    float sum = ex + __shfl_xor(ex, 1);
    sum += __shfl_xor(sum, 2);
    if (lane < 8) score[lane] = 0.5f * ex / sum;   // fold the channel-mean 0.5 in
}

// ---------------------------------------------------------------------------
// Kernel 2: MFMA gemm. Hc[n][col] = sum_k H[n][k]*Wcat[k][col], bf16 out.
// Wcat = [W[0] | W[1]] (K=128, N=128). Block: 256 thr = 4 waves, 64 rows.
// Wave computes 16 rows x 128 cols via 8 tiles of v_mfma_f32_16x16x32_bf16.
// A-frags straight from global f32 (each 32B chunk used fully); B staged
// transposed [n][k] in LDS (pad 136) so B-frags are contiguous b128 reads.
// Layouts: A row=lane&15, k=(lane>>4)*8+j; B col=lane&15, same k;
// D col=lane&15, row=(lane>>4)*4+reg  [m89-verified].
// ---------------------------------------------------------------------------
__global__ __launch_bounds__(256) void gemm_kernel(const float* __restrict__ H,
                                                   const float* __restrict__ W,
                                                   unsigned short* __restrict__ Hc, int N) {
    __shared__ unsigned short Bs[128 * 136];   // [n][k] bf16, padded row stride

    const int t = threadIdx.x;
    // stage Wcat -> Bs transposed; coalesced global reads (i = k*128 + n)
    for (int i = t; i < 128 * 128; i += 256) {
        const int k = i >> 7, n = i & 127;
        const int c = n >> 6, nn = n & 63;
        Bs[n * 136 + k] = f2bf_rn(W[c * (D_IN * D_OUT) + k * D_OUT + nn]);
    }

    const int lane = t & 63;
    const int wr   = t >> 6;                  // wave 0..3
    const int kg   = lane >> 4;               // k-group 0..3
    const int l15  = lane & 15;
    const int row0 = blockIdx.x * 64;

    int arow = row0 + wr * 16 + l15;
    if (arow >= N) arow = N - 1;              // clamp; stores are guarded

    // A fragments: 4 K-steps x 8 bf16 (global f32 -> bf16, RNE)
    bf16x8 afrag[4];
    const float* hrow = H + (size_t)arow * D_IN;
    #pragma unroll
    for (int s = 0; s < 4; ++s) {
        const int k0 = s * 32 + kg * 8;
        const float4 f0 = *reinterpret_cast<const float4*>(hrow + k0);
        const float4 f1 = *reinterpret_cast<const float4*>(hrow + k0 + 4);
        bf16x8 av;
        av[0] = (short)f2bf_rn(f0.x); av[1] = (short)f2bf_rn(f0.y);
        av[2] = (short)f2bf_rn(f0.z); av[3] = (short)f2bf_rn(f0.w);
        av[4] = (short)f2bf_rn(f1.x); av[5] = (short)f2bf_rn(f1.y);
        av[6] = (short)f2bf_rn(f1.z); av[7] = (short)f2bf_rn(f1.w);
        afrag[s] = av;
    }
    __syncthreads();                          // Bs ready

    #pragma unroll
    for (int nt = 0; nt < 8; ++nt) {
        const int n = nt * 16 + l15;
        f32x4 acc = {0.f, 0.f, 0.f, 0.f};
        #pragma unroll
        for (int s = 0; s < 4; ++s) {
            const bf16x8 bfrag =
                *reinterpret_cast<const bf16x8*>(&Bs[n * 136 + s * 32 + kg * 8]);
            acc = __builtin_amdgcn_mfma_f32_16x16x32_bf16(afrag[s], bfrag, acc, 0, 0, 0);
        }
        #pragma unroll
        for (int r = 0; r < 4; ++r) {
            const int drow = row0 + wr * 16 + kg * 4 + r;
            if (drow < N) Hc[(size_t)drow * COLS + n] = f2bf_rn(acc[r]);
        }
    }
}

// ---------------------------------------------------------------------------
// Kernel 3: LDS-aggregated histogram of buckets (bucket = row >> 6)
// ---------------------------------------------------------------------------
__global__ __launch_bounds__(1024) void hist_kernel(const int* __restrict__ rows,
                                                    unsigned* __restrict__ counts,
                                                    int TE, int NB) {
    __shared__ unsigned h[MAXNB];
    const int t = threadIdx.x;
    for (int i = t; i < MAXNB; i += 1024) h[i] = 0u;
    __syncthreads();
    for (int e = blockIdx.x * 1024 + t; e < TE; e += gridDim.x * 1024)
        atomicAdd(&h[rows[e] >> 6], 1u);
    __syncthreads();
    for (int i = t; i < NB; i += 1024)
        if (h[i]) atomicAdd(&counts[i], h[i]);
}

// ---------------------------------------------------------------------------
// Kernel 4: exclusive scan of counts -> offsets (and cursor copy). 1 block.
// ---------------------------------------------------------------------------
__global__ __launch_bounds__(1024) void scan_kernel(const unsigned* __restrict__ counts,
                                                    unsigned* __restrict__ offsets,
                                                    unsigned* __restrict__ cursor, int n) {
    __shared__ unsigned part[1024];
    const int t = threadIdx.x;
    const int chunk = (n + 1023) >> 10;
    const int s = t * chunk;
    const int e = min(s + chunk, n);
    unsigned sum = 0;
    for (int i = s; i < e; ++i) sum += counts[i];
    part[t] = sum;
    __syncthreads();
    for (int d = 1; d < 1024; d <<= 1) {
        unsigned v = (t >= d) ? part[t - d] : 0u;
        __syncthreads();
        part[t] += v;
        __syncthreads();
    }
    unsigned run = (t == 0) ? 0u : part[t - 1];
    for (int i = s; i < e; ++i) {
        const unsigned c = counts[i];
        offsets[i] = run;
        cursor[i]  = run;
        run += c;
    }
}

// ---------------------------------------------------------------------------
// Kernel 5: scatter with LDS counting-sort for COALESCED erec writes.
// Phase 1: load 4096 edges, LDS hist (rank captured from the same atomic).
// Phase 2: block scan -> local base; one global cursor atomic per bucket.
// Phase 3: place record + its global dst into sorted LDS order.
// Phase 4: flush in sorted order -> consecutive threads, consecutive addrs.
// record.x = col | (row_in_bucket << 16); record.y = bf16(w0)|bf16(w1)<<16
// ---------------------------------------------------------------------------
constexpr int SC_T   = 1024;
constexpr int SC_EPT = 4;
constexpr int SC_CH  = SC_T * SC_EPT;   // 4096 edges per block

__global__ __launch_bounds__(SC_T) void scatter_kernel(const int* __restrict__ rows,
                                                       const int* __restrict__ cols,
                                                       const float* __restrict__ vals,
                                                       const float* __restrict__ score,
                                                       unsigned* __restrict__ cursor,
                                                       uint2* __restrict__ erec,
                                                       int TE, int Eper, int NB) {
    __shared__ unsigned lh[MAXNB];                 // local hist
    __shared__ unsigned lbase[MAXNB];              // local exclusive offsets
    __shared__ unsigned gbase[MAXNB];              // claimed global bases
    __shared__ unsigned part[SC_T];                // scan temp
    __shared__ __align__(16) uint2 srec[SC_CH];    // 32 KB sorted records
    __shared__ unsigned sdst[SC_CH];               // 16 KB global dst per record
    __shared__ float ssc[8];

    const int t  = threadIdx.x;
    const int e0 = blockIdx.x * SC_CH;

    if (t < 8) ssc[t] = score[t];
    for (int i = t; i < MAXNB; i += SC_T) lh[i] = 0u;
    __syncthreads();

    unsigned bk[SC_EPT], rank[SC_EPT], meta[SC_EPT], wpk[SC_EPT];
    #pragma unroll
    for (int k = 0; k < SC_EPT; ++k) {
        const int e = e0 + k * SC_T + t;
        bk[k] = 0xffffffffu;
        if (e < TE) {
            const int row = rows[e];
            const int col = cols[e];
            const float v = vals[e];
            const int  a  = e / Eper;
            bk[k]   = (unsigned)(row >> 6);
            rank[k] = atomicAdd(&lh[bk[k]], 1u);
            meta[k] = (unsigned)col | ((unsigned)(row & 63) << 16);
            wpk[k]  = (unsigned)f2bf_rn(ssc[a] * v) |
                      ((unsigned)f2bf_rn(ssc[4 + a] * v) << 16);
        }
    }
    __syncthreads();

    // block-wide exclusive scan of lh[0..NB)
    const unsigned myc = (t < NB) ? lh[t] : 0u;
    part[t] = myc;
    __syncthreads();
    for (int d = 1; d < SC_T; d <<= 1) {
        unsigned v = (t >= d) ? part[t - d] : 0u;
        __syncthreads();
        part[t] += v;
        __syncthreads();
    }
    if (t < NB) {
        lbase[t] = part[t] - myc;
        gbase[t] = myc ? atomicAdd(&cursor[t], myc) : 0u;
    }
    __syncthreads();

    #pragma unroll
    for (int k = 0; k < SC_EPT; ++k) {
        if (bk[k] != 0xffffffffu) {
            const unsigned p = lbase[bk[k]] + rank[k];
            srec[p] = make_uint2(meta[k], wpk[k]);
            sdst[p] = gbase[bk[k]] + rank[k];
        }
    }
    __syncthreads();

    const unsigned cn = min((unsigned)(TE - e0), (unsigned)SC_CH);
    #pragma unroll
    for (int k = 0; k < SC_EPT; ++k) {
        const unsigned p = (unsigned)(k * SC_T + t);
        if (p < cn) erec[sdst[p]] = srec[p];
    }
}

// ---------------------------------------------------------------------------
// Kernel 6: bucket-SpMM, atomic-free register accumulation, 8-deep MLP.
// (unchanged from round 5)
// ---------------------------------------------------------------------------
__global__ __launch_bounds__(SPT) void bucketspmm_kernel(const uint2* __restrict__ erec,
                                                         const unsigned* __restrict__ offsets,
                                                         const unsigned* __restrict__ counts,
                                                         const unsigned* __restrict__ Hc32,
                                                         float* __restrict__ out, int N) {
    __shared__ __align__(16) uint2 srec[CAP];   // 36.9 KB sorted records
    __shared__ unsigned roff[RPB + 1];
    __shared__ unsigned rcur[RPB];

    const int t    = threadIdx.x;
    const int lane = t & 63;
    const int w    = t >> 6;                    // wave 0..7
    const int bucket = blockIdx.x;
    const unsigned start = offsets[bucket];
    const unsigned cnt   = counts[bucket];
    const int wsh = (lane < 32) ? 16 : 0;       // bf16 weight select per lane half

    float2 acc[8];
    #pragma unroll
    for (int r = 0; r < 8; ++r) acc[r] = make_float2(0.f, 0.f);

    for (unsigned cb = 0; cb < cnt; cb += CAP) {
        const unsigned cn = min(cnt - cb, (unsigned)CAP);

        if (t < RPB) roff[t] = 0u;
        __syncthreads();

        // load records into registers + histogram rib
        uint2 rec[RPT];
        #pragma unroll
        for (int k = 0; k < RPT; ++k) {
            const unsigned idx = (unsigned)(k * SPT + t);
            rec[k] = make_uint2(0xffffffffu, 0u);
            if (idx < cn) {
                rec[k] = erec[start + cb + idx];
                atomicAdd(&roff[rec[k].x >> 16], 1u);
            }
        }
        __syncthreads();

        // exclusive scan of 64 counts by wave 0
        if (t < 64) {
            const unsigned v = roff[t];
            unsigned incl = v;
            #pragma unroll
            for (int d = 1; d < 64; d <<= 1) {
                const unsigned nb = __shfl_up(incl, d);
                if (lane >= d) incl += nb;
            }
            const unsigned excl = incl - v;
            roff[t] = excl;
            rcur[t] = excl;
            if (t == 0) roff[RPB] = cn;
        }
        __syncthreads();

        // scatter records into row-sorted LDS order
        #pragma unroll
        for (int k = 0; k < RPT; ++k) {
            if (rec[k].x != 0xffffffffu) {
                const unsigned rib = rec[k].x >> 16;
                const unsigned pos = atomicAdd(&rcur[rib], 1u);
                srec[pos] = make_uint2(rec[k].x & 0xffffu, rec[k].y);
            }
        }
        __syncthreads();

        // register-accumulating SpMM over this chunk, 8 records in flight
        #pragma unroll
        for (int rr = 0; rr < 8; ++rr) {
            const int r = w * 8 + rr;
            unsigned j = roff[r];
            const unsigned e = roff[r + 1];
            float2 a = acc[rr];

            while (j + 8 <= e) {
                float    wv8[8];
                unsigned hv8[8];
                #pragma unroll
                for (int k = 0; k < 8; ++k) {
                    const uint2 rc = srec[j + k];
                    hv8[k] = Hc32[(rc.x << 6) + lane];
                    wv8[k] = __uint_as_float((rc.y << wsh) & 0xffff0000u);
                }
                #pragma unroll
                for (int k = 0; k < 8; ++k) {
                    a.x += wv8[k] * __uint_as_float(hv8[k] << 16);
                    a.y += wv8[k] * __uint_as_float(hv8[k] & 0xffff0000u);
                }
                j += 8;
            }
            for (; j < e; ++j) {
                const uint2 rc = srec[j];
                const unsigned hv = Hc32[(rc.x << 6) + lane];
                const float wv = __uint_as_float((rc.y << wsh) & 0xffff0000u);
                a.x += wv * __uint_as_float(hv << 16);
                a.y += wv * __uint_as_float(hv & 0xffff0000u);
            }
            acc[rr] = a;
        }
        __syncthreads();
    }

    // combine channel halves and store (covers zero rows too)
    const int row0 = bucket * RPB + w * 8;
    #pragma unroll
    for (int rr = 0; rr < 8; ++rr) {
        float2 a = acc[rr];
        a.x += __shfl_xor(a.x, 32);
        a.y += __shfl_xor(a.y, 32);
        const int row = row0 + rr;
        if (lane < 32 && row < N) {
            *reinterpret_cast<float2*>(out + (size_t)row * D_OUT + lane * 2) = a;
        }
    }
}

// ---------------------------------------------------------------------------
extern "C" void kernel_launch(void* const* d_in, const int* in_sizes, int n_in,
                              void* d_out, int out_size, void* d_ws, size_t ws_size,
                              hipStream_t stream) {
    const float* H    = (const float*)d_in[0];  // [N,128]
    const float* vals = (const float*)d_in[1];  // [4,E]
    const float* W    = (const float*)d_in[2];  // [2,128,64]
    const float* att  = (const float*)d_in[3];  // [2,128,4]
    const int*   rows = (const int*)d_in[4];    // [4,E]
    const int*   cols = (const int*)d_in[5];    // [4,E]

    const int N    = in_sizes[0] / D_IN;        // 50000
    const int TE   = in_sizes[1];               // 3.2M
    const int Eper = TE / NUM_A;                // 800000
    const int NB   = (N + RPB - 1) / RPB;       // 782

    char* ws = (char*)d_ws;
    size_t off = 0;
    float* ws_score = (float*)(ws + off);          off += 256;
    unsigned short* ws_Hc = (unsigned short*)(ws + off);
    off += (size_t)N * COLS * sizeof(unsigned short);
    off = (off + 255) & ~(size_t)255;
    unsigned* counts  = (unsigned*)(ws + off);     off += (size_t)MAXNB * sizeof(unsigned);
    unsigned* offsets = (unsigned*)(ws + off);     off += (size_t)MAXNB * sizeof(unsigned);
    unsigned* cursor  = (unsigned*)(ws + off);     off += (size_t)MAXNB * sizeof(unsigned);
    off = (off + 255) & ~(size_t)255;
    uint2* erec       = (uint2*)(ws + off);        off += (size_t)TE * sizeof(uint2);

    score_kernel<<<1, 64, 0, stream>>>(att, ws_score, counts, NB);

    gemm_kernel<<<(N + 63) / 64, 256, 0, stream>>>(H, W, ws_Hc, N);

    hist_kernel<<<512, 1024, 0, stream>>>(rows, counts, TE, NB);
    scan_kernel<<<1, 1024, 0, stream>>>(counts, offsets, cursor, NB);

    const int sblocks = (TE + SC_CH - 1) / SC_CH;
    scatter_kernel<<<sblocks, SC_T, 0, stream>>>(rows, cols, vals, ws_score,
                                                 cursor, erec, TE, Eper, NB);

    bucketspmm_kernel<<<NB, SPT, 0, stream>>>(erec, offsets, counts,
                                              (const unsigned*)ws_Hc,
                                              (float*)d_out, N);
}

// Round 7
// 242.153 us; speedup vs baseline: 6.3011x; 1.1486x over previous
//
#include <hip/hip_runtime.h>

// Problem constants (fixed by the reference file)
constexpr int D_IN  = 128;
constexpr int D_OUT = 64;
constexpr int NCH   = 2;
constexpr int NUM_A = 4;
constexpr int COLS  = NCH * D_OUT;     // 128 bf16 per Hc row (ch0 64 | ch1 64)
constexpr int RPB   = 64;              // rows per bucket
constexpr int MAXNB = 800;             // LDS cap (N up to 51200)
constexpr int CAP   = 4608;            // spmm sorted-record LDS capacity per chunk
constexpr int SPT   = 512;             // spmm block threads
constexpr int RPT   = CAP / SPT;       // 9 records held per thread
constexpr int CAPB  = 6144;            // padded per-bucket erec capacity (mean 4093, sd 64)

typedef __attribute__((ext_vector_type(8))) short bf16x8;   // 8 bf16 in 4 VGPRs
typedef __attribute__((ext_vector_type(4))) float f32x4;

__device__ inline unsigned short f2bf_rn(float f) {
    unsigned u = __float_as_uint(f);
    return (unsigned short)((u + 0x7fffu + ((u >> 16) & 1u)) >> 16);
}

// ---------------------------------------------------------------------------
// Kernel 1: score[c][a] = 0.5 * softmax_a( mean_d att[c][d][a] )
// Also inits the bucket counters: padded path -> cursor[i] = i*CAPB,
// exact path -> counts[i] = 0.   (replaces a memset launch)
// ---------------------------------------------------------------------------
__global__ __launch_bounds__(64) void score_kernel(const float* __restrict__ att,
                                                   float* __restrict__ score,
                                                   unsigned* __restrict__ cinit,
                                                   int NB, int padded) {
    int lane = threadIdx.x;
    for (int i = lane; i < NB; i += 64)
        cinit[i] = padded ? (unsigned)i * (unsigned)CAPB : 0u;
    int c = lane >> 2, a = lane & 3;
    float s = 0.0f;
    if (lane < 8) {
        const float* p = att + c * (D_IN * NUM_A) + a;
        for (int d = 0; d < D_IN; ++d) s += p[d * NUM_A];
        s *= (1.0f / D_IN);
    }
    float m = fmaxf(s, __shfl_xor(s, 1));
    m = fmaxf(m, __shfl_xor(m, 2));
    float ex = __expf(s - m);
    float sum = ex + __shfl_xor(ex, 1);
    sum += __shfl_xor(sum, 2);
    if (lane < 8) score[lane] = 0.5f * ex / sum;   // fold the channel-mean 0.5 in
}

// ---------------------------------------------------------------------------
// Kernel 2: MFMA gemm (verified round 6). Hc[n][col] = sum_k H[n][k]*Wcat[k][col].
// ---------------------------------------------------------------------------
__global__ __launch_bounds__(256) void gemm_kernel(const float* __restrict__ H,
                                                   const float* __restrict__ W,
                                                   unsigned short* __restrict__ Hc, int N) {
    __shared__ unsigned short Bs[128 * 136];   // [n][k] bf16, padded row stride

    const int t = threadIdx.x;
    for (int i = t; i < 128 * 128; i += 256) {
        const int k = i >> 7, n = i & 127;
        const int c = n >> 6, nn = n & 63;
        Bs[n * 136 + k] = f2bf_rn(W[c * (D_IN * D_OUT) + k * D_OUT + nn]);
    }

    const int lane = t & 63;
    const int wr   = t >> 6;
    const int kg   = lane >> 4;
    const int l15  = lane & 15;
    const int row0 = blockIdx.x * 64;

    int arow = row0 + wr * 16 + l15;
    if (arow >= N) arow = N - 1;

    bf16x8 afrag[4];
    const float* hrow = H + (size_t)arow * D_IN;
    #pragma unroll
    for (int s = 0; s < 4; ++s) {
        const int k0 = s * 32 + kg * 8;
        const float4 f0 = *reinterpret_cast<const float4*>(hrow + k0);
        const float4 f1 = *reinterpret_cast<const float4*>(hrow + k0 + 4);
        bf16x8 av;
        av[0] = (short)f2bf_rn(f0.x); av[1] = (short)f2bf_rn(f0.y);
        av[2] = (short)f2bf_rn(f0.z); av[3] = (short)f2bf_rn(f0.w);
        av[4] = (short)f2bf_rn(f1.x); av[5] = (short)f2bf_rn(f1.y);
        av[6] = (short)f2bf_rn(f1.z); av[7] = (short)f2bf_rn(f1.w);
        afrag[s] = av;
    }
    __syncthreads();

    #pragma unroll
    for (int nt = 0; nt < 8; ++nt) {
        const int n = nt * 16 + l15;
        f32x4 acc = {0.f, 0.f, 0.f, 0.f};
        #pragma unroll
        for (int s = 0; s < 4; ++s) {
            const bf16x8 bfrag =
                *reinterpret_cast<const bf16x8*>(&Bs[n * 136 + s * 32 + kg * 8]);
            acc = __builtin_amdgcn_mfma_f32_16x16x32_bf16(afrag[s], bfrag, acc, 0, 0, 0);
        }
        #pragma unroll
        for (int r = 0; r < 4; ++r) {
            const int drow = row0 + wr * 16 + kg * 4 + r;
            if (drow < N) Hc[(size_t)drow * COLS + n] = f2bf_rn(acc[r]);
        }
    }
}

// ---------------------------------------------------------------------------
// Kernel 3 (fallback path only): LDS-aggregated histogram of buckets
// ---------------------------------------------------------------------------
__global__ __launch_bounds__(1024) void hist_kernel(const int* __restrict__ rows,
                                                    unsigned* __restrict__ counts,
                                                    int TE, int NB) {
    __shared__ unsigned h[MAXNB];
    const int t = threadIdx.x;
    for (int i = t; i < MAXNB; i += 1024) h[i] = 0u;
    __syncthreads();
    for (int e = blockIdx.x * 1024 + t; e < TE; e += gridDim.x * 1024)
        atomicAdd(&h[rows[e] >> 6], 1u);
    __syncthreads();
    for (int i = t; i < NB; i += 1024)
        if (h[i]) atomicAdd(&counts[i], h[i]);
}

// ---------------------------------------------------------------------------
// Kernel 4 (fallback path only): exclusive scan of counts -> offsets + cursor
// ---------------------------------------------------------------------------
__global__ __launch_bounds__(1024) void scan_kernel(const unsigned* __restrict__ counts,
                                                    unsigned* __restrict__ offsets,
                                                    unsigned* __restrict__ cursor, int n) {
    __shared__ unsigned part[1024];
    const int t = threadIdx.x;
    const int chunk = (n + 1023) >> 10;
    const int s = t * chunk;
    const int e = min(s + chunk, n);
    unsigned sum = 0;
    for (int i = s; i < e; ++i) sum += counts[i];
    part[t] = sum;
    __syncthreads();
    for (int d = 1; d < 1024; d <<= 1) {
        unsigned v = (t >= d) ? part[t - d] : 0u;
        __syncthreads();
        part[t] += v;
        __syncthreads();
    }
    unsigned run = (t == 0) ? 0u : part[t - 1];
    for (int i = s; i < e; ++i) {
        const unsigned c = counts[i];
        offsets[i] = run;
        cursor[i]  = run;
        run += c;
    }
}

// ---------------------------------------------------------------------------
// Kernel 5: scatter with LDS counting-sort for COALESCED erec writes.
// Works for both paths: cursor holds append bases (padded: b*CAPB segments).
// ---------------------------------------------------------------------------
constexpr int SC_T   = 1024;
constexpr int SC_EPT = 4;
constexpr int SC_CH  = SC_T * SC_EPT;   // 4096 edges per block

__global__ __launch_bounds__(SC_T) void scatter_kernel(const int* __restrict__ rows,
                                                       const int* __restrict__ cols,
                                                       const float* __restrict__ vals,
                                                       const float* __restrict__ score,
                                                       unsigned* __restrict__ cursor,
                                                       uint2* __restrict__ erec,
                                                       int TE, int Eper, int NB) {
    __shared__ unsigned lh[MAXNB];                 // local hist
    __shared__ unsigned lbase[MAXNB];              // local exclusive offsets
    __shared__ unsigned gbase[MAXNB];              // claimed global bases
    __shared__ unsigned part[SC_T];                // scan temp
    __shared__ __align__(16) uint2 srec[SC_CH];    // 32 KB sorted records
    __shared__ unsigned sdst[SC_CH];               // 16 KB global dst per record
    __shared__ float ssc[8];

    const int t  = threadIdx.x;
    const int e0 = blockIdx.x * SC_CH;

    if (t < 8) ssc[t] = score[t];
    for (int i = t; i < MAXNB; i += SC_T) lh[i] = 0u;
    __syncthreads();

    unsigned bk[SC_EPT], rank[SC_EPT], meta[SC_EPT], wpk[SC_EPT];
    #pragma unroll
    for (int k = 0; k < SC_EPT; ++k) {
        const int e = e0 + k * SC_T + t;
        bk[k] = 0xffffffffu;
        if (e < TE) {
            const int row = rows[e];
            const int col = cols[e];
            const float v = vals[e];
            const int  a  = e / Eper;
            bk[k]   = (unsigned)(row >> 6);
            rank[k] = atomicAdd(&lh[bk[k]], 1u);
            meta[k] = (unsigned)col | ((unsigned)(row & 63) << 16);
            wpk[k]  = (unsigned)f2bf_rn(ssc[a] * v) |
                      ((unsigned)f2bf_rn(ssc[4 + a] * v) << 16);
        }
    }
    __syncthreads();

    const unsigned myc = (t < NB) ? lh[t] : 0u;
    part[t] = myc;
    __syncthreads();
    for (int d = 1; d < SC_T; d <<= 1) {
        unsigned v = (t >= d) ? part[t - d] : 0u;
        __syncthreads();
        part[t] += v;
        __syncthreads();
    }
    if (t < NB) {
        lbase[t] = part[t] - myc;
        gbase[t] = myc ? atomicAdd(&cursor[t], myc) : 0u;
    }
    __syncthreads();

    #pragma unroll
    for (int k = 0; k < SC_EPT; ++k) {
        if (bk[k] != 0xffffffffu) {
            const unsigned p = lbase[bk[k]] + rank[k];
            srec[p] = make_uint2(meta[k], wpk[k]);
            sdst[p] = gbase[bk[k]] + rank[k];
        }
    }
    __syncthreads();

    const unsigned cn = min((unsigned)(TE - e0), (unsigned)SC_CH);
    #pragma unroll
    for (int k = 0; k < SC_EPT; ++k) {
        const unsigned p = (unsigned)(k * SC_T + t);
        if (p < cn) erec[sdst[p]] = srec[p];
    }
}

// ---------------------------------------------------------------------------
// Kernel 6: bucket-SpMM. Counting sort with per-wave split histogram +
// rank capture (single LDS-atomic round), then register accumulation with
// 16-deep MLP.  padded: start = bucket*CAPB, cnt = cursor[bucket]-start.
// ---------------------------------------------------------------------------
__global__ __launch_bounds__(SPT) void bucketspmm_kernel(const uint2* __restrict__ erec,
                                                         const unsigned* __restrict__ offsets,
                                                         const unsigned* __restrict__ counts,
                                                         const unsigned* __restrict__ cursor,
                                                         const unsigned* __restrict__ Hc32,
                                                         float* __restrict__ out,
                                                         int N, int padded) {
    __shared__ __align__(16) uint2 srec[CAP];   // 36.9 KB sorted records
    __shared__ unsigned roff8[8 * 68];          // per-wave rib hist -> per-wave base
    __shared__ unsigned roff[RPB + 1];          // per-rib exclusive offsets

    const int t    = threadIdx.x;
    const int lane = t & 63;
    const int w    = t >> 6;                    // wave 0..7
    const int bucket = blockIdx.x;
    unsigned start, cnt;
    if (padded) {
        start = (unsigned)bucket * (unsigned)CAPB;
        cnt   = cursor[bucket] - start;
    } else {
        start = offsets[bucket];
        cnt   = counts[bucket];
    }
    const int wsh = (lane < 32) ? 16 : 0;       // bf16 weight select per lane half

    float2 acc[8];
    #pragma unroll
    for (int r = 0; r < 8; ++r) acc[r] = make_float2(0.f, 0.f);

    for (unsigned cb = 0; cb < cnt; cb += CAP) {
        const unsigned cn = min(cnt - cb, (unsigned)CAP);

        for (int i = t; i < 8 * 68; i += SPT) roff8[i] = 0u;
        __syncthreads();

        // load records + per-wave rib histogram, capturing rank
        uint2 rec[RPT];
        unsigned rank[RPT];
        #pragma unroll
        for (int k = 0; k < RPT; ++k) {
            const unsigned idx = (unsigned)(k * SPT + t);
            rec[k] = make_uint2(0xffffffffu, 0u);
            if (idx < cn) {
                rec[k] = erec[start + cb + idx];
                rank[k] = atomicAdd(&roff8[w * 68 + (rec[k].x >> 16)], 1u);
            }
        }
        __syncthreads();

        // combine per-wave hists (thread t = rib t) + wave-0 exclusive scan
        if (t < 64) {
            unsigned run = 0;
            #pragma unroll
            for (int w2 = 0; w2 < 8; ++w2) {
                const unsigned v = roff8[w2 * 68 + t];
                roff8[w2 * 68 + t] = run;       // per-wave exclusive base within rib
                run += v;
            }
            unsigned incl = run;
            #pragma unroll
            for (int d = 1; d < 64; d <<= 1) {
                const unsigned nb = __shfl_up(incl, d);
                if (lane >= d) incl += nb;
            }
            roff[t] = incl - run;               // rib exclusive offset
            if (t == 63) roff[RPB] = incl;      // == cn
        }
        __syncthreads();

        // place records into row-sorted LDS order (no second atomic round)
        #pragma unroll
        for (int k = 0; k < RPT; ++k) {
            if (rec[k].x != 0xffffffffu) {
                const unsigned rib = rec[k].x >> 16;
                const unsigned pos = roff[rib] + roff8[w * 68 + rib] + rank[k];
                srec[pos] = make_uint2(rec[k].x & 0xffffu, rec[k].y);
            }
        }
        __syncthreads();

        // register-accumulating SpMM, 16 records in flight
        #pragma unroll
        for (int rr = 0; rr < 8; ++rr) {
            const int r = w * 8 + rr;
            unsigned j = roff[r];
            const unsigned e = roff[r + 1];
            float2 a = acc[rr];

            while (j + 16 <= e) {
                float    wv16[16];
                unsigned hv16[16];
                #pragma unroll
                for (int k = 0; k < 16; ++k) {
                    const uint2 rc = srec[j + k];
                    hv16[k] = Hc32[(rc.x << 6) + lane];
                    wv16[k] = __uint_as_float((rc.y << wsh) & 0xffff0000u);
                }
                #pragma unroll
                for (int k = 0; k < 16; ++k) {
                    a.x += wv16[k] * __uint_as_float(hv16[k] << 16);
                    a.y += wv16[k] * __uint_as_float(hv16[k] & 0xffff0000u);
                }
                j += 16;
            }
            while (j + 4 <= e) {
                float    wv4[4];
                unsigned hv4[4];
                #pragma unroll
                for (int k = 0; k < 4; ++k) {
                    const uint2 rc = srec[j + k];
                    hv4[k] = Hc32[(rc.x << 6) + lane];
                    wv4[k] = __uint_as_float((rc.y << wsh) & 0xffff0000u);
                }
                #pragma unroll
                for (int k = 0; k < 4; ++k) {
                    a.x += wv4[k] * __uint_as_float(hv4[k] << 16);
                    a.y += wv4[k] * __uint_as_float(hv4[k] & 0xffff0000u);
                }
                j += 4;
            }
            for (; j < e; ++j) {
                const uint2 rc = srec[j];
                const unsigned hv = Hc32[(rc.x << 6) + lane];
                const float wv = __uint_as_float((rc.y << wsh) & 0xffff0000u);
                a.x += wv * __uint_as_float(hv << 16);
                a.y += wv * __uint_as_float(hv & 0xffff0000u);
            }
            acc[rr] = a;
        }
        __syncthreads();
    }

    // combine channel halves and store (covers zero rows too)
    const int row0 = bucket * RPB + w * 8;
    #pragma unroll
    for (int rr = 0; rr < 8; ++rr) {
        float2 a = acc[rr];
        a.x += __shfl_xor(a.x, 32);
        a.y += __shfl_xor(a.y, 32);
        const int row = row0 + rr;
        if (lane < 32 && row < N) {
            *reinterpret_cast<float2*>(out + (size_t)row * D_OUT + lane * 2) = a;
        }
    }
}

// ---------------------------------------------------------------------------
extern "C" void kernel_launch(void* const* d_in, const int* in_sizes, int n_in,
                              void* d_out, int out_size, void* d_ws, size_t ws_size,
                              hipStream_t stream) {
    const float* H    = (const float*)d_in[0];  // [N,128]
    const float* vals = (const float*)d_in[1];  // [4,E]
    const float* W    = (const float*)d_in[2];  // [2,128,64]
    const float* att  = (const float*)d_in[3];  // [2,128,4]
    const int*   rows = (const int*)d_in[4];    // [4,E]
    const int*   cols = (const int*)d_in[5];    // [4,E]

    const int N    = in_sizes[0] / D_IN;        // 50000
    const int TE   = in_sizes[1];               // 3.2M
    const int Eper = TE / NUM_A;                // 800000
    const int NB   = (N + RPB - 1) / RPB;       // 782

    char* ws = (char*)d_ws;
    size_t off = 0;
    float* ws_score = (float*)(ws + off);          off += 256;
    unsigned short* ws_Hc = (unsigned short*)(ws + off);
    off += (size_t)N * COLS * sizeof(unsigned short);
    off = (off + 255) & ~(size_t)255;
    unsigned* counts  = (unsigned*)(ws + off);     off += (size_t)MAXNB * sizeof(unsigned);
    unsigned* offsets = (unsigned*)(ws + off);     off += (size_t)MAXNB * sizeof(unsigned);
    unsigned* cursor  = (unsigned*)(ws + off);     off += (size_t)MAXNB * sizeof(unsigned);
    off = (off + 255) & ~(size_t)255;
    uint2* erec       = (uint2*)(ws + off);

    // padded path needs NB*CAPB records; fallback needs TE records
    const size_t need_padded = off + (size_t)NB * CAPB * sizeof(uint2);
    const int padded = (ws_size >= need_padded) ? 1 : 0;

    score_kernel<<<1, 64, 0, stream>>>(att, ws_score, padded ? cursor : counts,
                                       NB, padded);

    gemm_kernel<<<(N + 63) / 64, 256, 0, stream>>>(H, W, ws_Hc, N);

    if (!padded) {
        hist_kernel<<<512, 1024, 0, stream>>>(rows, counts, TE, NB);
        scan_kernel<<<1, 1024, 0, stream>>>(counts, offsets, cursor, NB);
    }

    const int sblocks = (TE + SC_CH - 1) / SC_CH;
    scatter_kernel<<<sblocks, SC_T, 0, stream>>>(rows, cols, vals, ws_score,
                                                 cursor, erec, TE, Eper, NB);

    bucketspmm_kernel<<<NB, SPT, 0, stream>>>(erec, offsets, counts, cursor,
                                              (const unsigned*)ws_Hc,
                                              (float*)d_out, N, padded);
}

// Round 8
// 233.436 us; speedup vs baseline: 6.5364x; 1.0373x over previous
//
#include <hip/hip_runtime.h>
#include <hip/hip_fp16.h>

// Problem constants (fixed by the reference file)
constexpr int D_IN  = 128;
constexpr int D_OUT = 64;
constexpr int NCH   = 2;
constexpr int NUM_A = 4;
constexpr int COLS  = NCH * D_OUT;     // 128 f16 per Hc row (ch0 64 | ch1 64)
constexpr int RPB   = 64;              // rows per bucket
constexpr int MAXNB = 800;             // LDS cap (N up to 51200)
constexpr int CAP   = 4608;            // spmm sorted-record LDS capacity per chunk
constexpr int SPT   = 512;             // spmm block threads
constexpr int RPT   = CAP / SPT;       // 9 records held per thread
constexpr int CAPB  = 6144;            // padded per-bucket erec capacity (mean 4092, sd 64)

typedef __attribute__((ext_vector_type(8))) short bf16x8;   // 8 bf16 in 4 VGPRs
typedef __attribute__((ext_vector_type(4))) float f32x4;

__device__ inline unsigned short f2bf_rn(float f) {
    unsigned u = __float_as_uint(f);
    return (unsigned short)((u + 0x7fffu + ((u >> 16) & 1u)) >> 16);
}
__device__ inline unsigned short f2h(float f) {
    _Float16 h = (_Float16)f;                    // v_cvt_f16_f32 (RNE)
    unsigned short u; __builtin_memcpy(&u, &h, 2); return u;
}
__device__ inline __half2 u2h2(unsigned u) {
    __half2 h; __builtin_memcpy(&h, &u, 4); return h;
}

// ---------------------------------------------------------------------------
// Kernel 1: score[c][a] = 0.5 * softmax_a( mean_d att[c][d][a] )
// Also inits the bucket cursors (padded: cursor[i]=i*CAPB; exact: counts=0).
// ---------------------------------------------------------------------------
__global__ __launch_bounds__(64) void score_kernel(const float* __restrict__ att,
                                                   float* __restrict__ score,
                                                   unsigned* __restrict__ cinit,
                                                   int NB, int padded) {
    int lane = threadIdx.x;
    for (int i = lane; i < NB; i += 64)
        cinit[i] = padded ? (unsigned)i * (unsigned)CAPB : 0u;
    int c = lane >> 2, a = lane & 3;
    float s = 0.0f;
    if (lane < 8) {
        const float* p = att + c * (D_IN * NUM_A) + a;
        for (int d = 0; d < D_IN; ++d) s += p[d * NUM_A];
        s *= (1.0f / D_IN);
    }
    float m = fmaxf(s, __shfl_xor(s, 1));
    m = fmaxf(m, __shfl_xor(m, 2));
    float ex = __expf(s - m);
    float sum = ex + __shfl_xor(ex, 1);
    sum += __shfl_xor(sum, 2);
    if (lane < 8) score[lane] = 0.5f * ex / sum;   // fold the channel-mean 0.5 in
}

// ---------------------------------------------------------------------------
// Kernel 2: MFMA gemm (layout verified r6). Hc[n][col] = sum_k H[n][k]*Wcat[k][col].
// Inputs rounded to bf16 for MFMA; OUTPUT now stored as f16 (for pk_fma spmm).
// ---------------------------------------------------------------------------
__global__ __launch_bounds__(256) void gemm_kernel(const float* __restrict__ H,
                                                   const float* __restrict__ W,
                                                   unsigned short* __restrict__ Hc, int N) {
    __shared__ unsigned short Bs[128 * 136];   // [n][k] bf16, padded row stride

    const int t = threadIdx.x;
    for (int i = t; i < 128 * 128; i += 256) {
        const int k = i >> 7, n = i & 127;
        const int c = n >> 6, nn = n & 63;
        Bs[n * 136 + k] = f2bf_rn(W[c * (D_IN * D_OUT) + k * D_OUT + nn]);
    }

    const int lane = t & 63;
    const int wr   = t >> 6;
    const int kg   = lane >> 4;
    const int l15  = lane & 15;
    const int row0 = blockIdx.x * 64;

    int arow = row0 + wr * 16 + l15;
    if (arow >= N) arow = N - 1;

    bf16x8 afrag[4];
    const float* hrow = H + (size_t)arow * D_IN;
    #pragma unroll
    for (int s = 0; s < 4; ++s) {
        const int k0 = s * 32 + kg * 8;
        const float4 f0 = *reinterpret_cast<const float4*>(hrow + k0);
        const float4 f1 = *reinterpret_cast<const float4*>(hrow + k0 + 4);
        bf16x8 av;
        av[0] = (short)f2bf_rn(f0.x); av[1] = (short)f2bf_rn(f0.y);
        av[2] = (short)f2bf_rn(f0.z); av[3] = (short)f2bf_rn(f0.w);
        av[4] = (short)f2bf_rn(f1.x); av[5] = (short)f2bf_rn(f1.y);
        av[6] = (short)f2bf_rn(f1.z); av[7] = (short)f2bf_rn(f1.w);
        afrag[s] = av;
    }
    __syncthreads();

    #pragma unroll
    for (int nt = 0; nt < 8; ++nt) {
        const int n = nt * 16 + l15;
        f32x4 acc = {0.f, 0.f, 0.f, 0.f};
        #pragma unroll
        for (int s = 0; s < 4; ++s) {
            const bf16x8 bfrag =
                *reinterpret_cast<const bf16x8*>(&Bs[n * 136 + s * 32 + kg * 8]);
            acc = __builtin_amdgcn_mfma_f32_16x16x32_bf16(afrag[s], bfrag, acc, 0, 0, 0);
        }
        #pragma unroll
        for (int r = 0; r < 4; ++r) {
            const int drow = row0 + wr * 16 + kg * 4 + r;
            if (drow < N) Hc[(size_t)drow * COLS + n] = f2h(acc[r]);
        }
    }
}

// ---------------------------------------------------------------------------
// Kernel 3 (fallback path only): LDS-aggregated histogram of buckets
// ---------------------------------------------------------------------------
__global__ __launch_bounds__(1024) void hist_kernel(const int* __restrict__ rows,
                                                    unsigned* __restrict__ counts,
                                                    int TE, int NB) {
    __shared__ unsigned h[MAXNB];
    const int t = threadIdx.x;
    for (int i = t; i < MAXNB; i += 1024) h[i] = 0u;
    __syncthreads();
    for (int e = blockIdx.x * 1024 + t; e < TE; e += gridDim.x * 1024)
        atomicAdd(&h[rows[e] >> 6], 1u);
    __syncthreads();
    for (int i = t; i < NB; i += 1024)
        if (h[i]) atomicAdd(&counts[i], h[i]);
}

// ---------------------------------------------------------------------------
// Kernel 4 (fallback path only): exclusive scan of counts -> offsets + cursor
// ---------------------------------------------------------------------------
__global__ __launch_bounds__(1024) void scan_kernel(const unsigned* __restrict__ counts,
                                                    unsigned* __restrict__ offsets,
                                                    unsigned* __restrict__ cursor, int n) {
    __shared__ unsigned part[1024];
    const int t = threadIdx.x;
    const int chunk = (n + 1023) >> 10;
    const int s = t * chunk;
    const int e = min(s + chunk, n);
    unsigned sum = 0;
    for (int i = s; i < e; ++i) sum += counts[i];
    part[t] = sum;
    __syncthreads();
    for (int d = 1; d < 1024; d <<= 1) {
        unsigned v = (t >= d) ? part[t - d] : 0u;
        __syncthreads();
        part[t] += v;
        __syncthreads();
    }
    unsigned run = (t == 0) ? 0u : part[t - 1];
    for (int i = s; i < e; ++i) {
        const unsigned c = counts[i];
        offsets[i] = run;
        cursor[i]  = run;
        run += c;
    }
}

// ---------------------------------------------------------------------------
// Kernel 5: scatter with LDS counting-sort for COALESCED erec writes.
// r8: bucket id packed into record bits 22-31 (sdst array removed; dst
// recomputed at flush); 3-level wave-shfl scan (4 barriers, was 21);
// SC_EPT=6. erec gets (col | rib<<16) with bk stripped; weights f16-packed.
// ---------------------------------------------------------------------------
constexpr int SC_T   = 1024;
constexpr int SC_EPT = 6;
constexpr int SC_CH  = SC_T * SC_EPT;   // 6144 edges per block

__global__ __launch_bounds__(SC_T) void scatter_kernel(const int* __restrict__ rows,
                                                       const int* __restrict__ cols,
                                                       const float* __restrict__ vals,
                                                       const float* __restrict__ score,
                                                       unsigned* __restrict__ cursor,
                                                       uint2* __restrict__ erec,
                                                       int TE, int Eper, int NB) {
    __shared__ unsigned lh[MAXNB];                 // local hist
    __shared__ unsigned lbase[MAXNB];              // local exclusive offsets
    __shared__ unsigned gbase[MAXNB];              // claimed global bases
    __shared__ unsigned wsum[16];                  // per-wave scan partials
    __shared__ __align__(16) uint2 srec[SC_CH];    // 48 KB sorted records
    __shared__ float ssc[8];

    const int t  = threadIdx.x;
    const int e0 = blockIdx.x * SC_CH;

    if (t < 8) ssc[t] = score[t];
    for (int i = t; i < MAXNB; i += SC_T) lh[i] = 0u;
    __syncthreads();

    unsigned bkrank[SC_EPT], meta[SC_EPT], wpk[SC_EPT];
    #pragma unroll
    for (int k = 0; k < SC_EPT; ++k) {
        const int e = e0 + k * SC_T + t;
        bkrank[k] = 0xffffffffu;
        if (e < TE) {
            const int row = rows[e];
            const int col = cols[e];
            const float v = vals[e];
            const int  a  = e / Eper;
            const unsigned bk = (unsigned)(row >> 6);
            const unsigned rk = atomicAdd(&lh[bk], 1u);
            bkrank[k] = (bk << 16) | rk;           // rk < 6144 fits 16 bits
            meta[k]   = (unsigned)col | ((unsigned)(row & 63) << 16) | (bk << 22);
            wpk[k]    = (unsigned)f2h(ssc[a] * v) |
                        ((unsigned)f2h(ssc[4 + a] * v) << 16);
        }
    }
    __syncthreads();

    // 3-level scan: NB <= 1024 so thread t owns bucket t
    const unsigned v = (t < NB) ? lh[t] : 0u;
    unsigned incl = v;
    #pragma unroll
    for (int d = 1; d < 64; d <<= 1) {
        const unsigned nb = __shfl_up(incl, d);
        if ((t & 63) >= d) incl += nb;
    }
    if ((t & 63) == 63) wsum[t >> 6] = incl;
    __syncthreads();
    if (t < 16) {
        const unsigned s = wsum[t];
        unsigned i2 = s;
        #pragma unroll
        for (int d = 1; d < 16; d <<= 1) {
            const unsigned nb = __shfl_up(i2, d);
            if (t >= d) i2 += nb;
        }
        wsum[t] = i2 - s;                          // exclusive wave base
    }
    __syncthreads();
    if (t < NB) {
        lbase[t] = incl - v + wsum[t >> 6];
        gbase[t] = v ? atomicAdd(&cursor[t], v) : 0u;
    }
    __syncthreads();

    #pragma unroll
    for (int k = 0; k < SC_EPT; ++k) {
        if (bkrank[k] != 0xffffffffu) {
            const unsigned p = lbase[bkrank[k] >> 16] + (bkrank[k] & 0xffffu);
            srec[p] = make_uint2(meta[k], wpk[k]);
        }
    }
    __syncthreads();

    const unsigned cn = min((unsigned)(TE - e0), (unsigned)SC_CH);
    #pragma unroll
    for (int k = 0; k < SC_EPT; ++k) {
        const unsigned p = (unsigned)(k * SC_T + t);
        if (p < cn) {
            const uint2 r = srec[p];
            const unsigned bk = r.x >> 22;
            const unsigned dst = gbase[bk] + (p - lbase[bk]);
            erec[dst] = make_uint2(r.x & 0x003fffffu, r.y);
        }
    }
}

// ---------------------------------------------------------------------------
// Kernel 6: bucket-SpMM. Single-atomic counting sort (r7) + packed-f16
// inner loop: per record = addr add + load + v_perm_b32 weight-dup +
// v_pk_fma_f16; f16 accumulators flushed to f32 every <=16 records.
// ---------------------------------------------------------------------------
__global__ __launch_bounds__(SPT) void bucketspmm_kernel(const uint2* __restrict__ erec,
                                                         const unsigned* __restrict__ offsets,
                                                         const unsigned* __restrict__ counts,
                                                         const unsigned* __restrict__ cursor,
                                                         const unsigned* __restrict__ Hc32,
                                                         float* __restrict__ out,
                                                         int N, int padded) {
    __shared__ __align__(16) uint2 srec[CAP];   // 36.9 KB sorted records
    __shared__ unsigned roff8[8 * 68];          // per-wave rib hist -> per-wave base
    __shared__ unsigned roff[RPB + 1];          // per-rib exclusive offsets

    const int t    = threadIdx.x;
    const int lane = t & 63;
    const int w    = t >> 6;                    // wave 0..7
    const int bucket = blockIdx.x;
    unsigned start, cnt;
    if (padded) {
        start = (unsigned)bucket * (unsigned)CAPB;
        cnt   = cursor[bucket] - start;
    } else {
        start = offsets[bucket];
        cnt   = counts[bucket];
    }
    // weight byte-perm selector: duplicate this lane-half's f16 into both halves
    const unsigned psel = (lane < 32) ? 0x01000100u : 0x03020302u;

    float2 acc[8];
    #pragma unroll
    for (int r = 0; r < 8; ++r) acc[r] = make_float2(0.f, 0.f);

    for (unsigned cb = 0; cb < cnt; cb += CAP) {
        const unsigned cn = min(cnt - cb, (unsigned)CAP);

        for (int i = t; i < 8 * 68; i += SPT) roff8[i] = 0u;
        __syncthreads();

        // load records + per-wave rib histogram, capturing rank
        uint2 rec[RPT];
        unsigned rank[RPT];
        #pragma unroll
        for (int k = 0; k < RPT; ++k) {
            const unsigned idx = (unsigned)(k * SPT + t);
            rec[k] = make_uint2(0xffffffffu, 0u);
            if (idx < cn) {
                rec[k] = erec[start + cb + idx];
                rank[k] = atomicAdd(&roff8[w * 68 + (rec[k].x >> 16)], 1u);
            }
        }
        __syncthreads();

        // combine per-wave hists (thread t = rib t) + wave-0 exclusive scan
        if (t < 64) {
            unsigned run = 0;
            #pragma unroll
            for (int w2 = 0; w2 < 8; ++w2) {
                const unsigned v = roff8[w2 * 68 + t];
                roff8[w2 * 68 + t] = run;       // per-wave exclusive base within rib
                run += v;
            }
            unsigned incl = run;
            #pragma unroll
            for (int d = 1; d < 64; d <<= 1) {
                const unsigned nb = __shfl_up(incl, d);
                if (lane >= d) incl += nb;
            }
            roff[t] = incl - run;               // rib exclusive offset
            if (t == 63) roff[RPB] = incl;      // == cn
        }
        __syncthreads();

        // place records into row-sorted LDS order (single atomic round)
        #pragma unroll
        for (int k = 0; k < RPT; ++k) {
            if (rec[k].x != 0xffffffffu) {
                const unsigned rib = rec[k].x >> 16;
                const unsigned pos = roff[rib] + roff8[w * 68 + rib] + rank[k];
                srec[pos] = make_uint2(rec[k].x & 0xffffu, rec[k].y);
            }
        }
        __syncthreads();

        // packed-f16 SpMM, 16 records in flight
        #pragma unroll
        for (int rr = 0; rr < 8; ++rr) {
            const int r = w * 8 + rr;
            unsigned j = roff[r];
            const unsigned e = roff[r + 1];
            float2 a = acc[rr];

            while (j + 16 <= e) {
                unsigned hv16[16], wv16[16];
                #pragma unroll
                for (int k = 0; k < 16; ++k) {
                    const uint2 rc = srec[j + k];
                    hv16[k] = Hc32[(rc.x << 6) + lane];
                    wv16[k] = __builtin_amdgcn_perm(rc.y, rc.y, psel);
                }
                __half2 h2a = u2h2(0u), h2b = u2h2(0u);
                #pragma unroll
                for (int k = 0; k < 16; k += 2) {
                    h2a = __hfma2(u2h2(hv16[k]),     u2h2(wv16[k]),     h2a);
                    h2b = __hfma2(u2h2(hv16[k + 1]), u2h2(wv16[k + 1]), h2b);
                }
                const __half2 hs = __hadd2(h2a, h2b);
                a.x += __low2float(hs);
                a.y += __high2float(hs);
                j += 16;
            }
            if (j < e) {
                __half2 h2 = u2h2(0u);
                while (j + 4 <= e) {
                    unsigned hv4[4], wv4[4];
                    #pragma unroll
                    for (int k = 0; k < 4; ++k) {
                        const uint2 rc = srec[j + k];
                        hv4[k] = Hc32[(rc.x << 6) + lane];
                        wv4[k] = __builtin_amdgcn_perm(rc.y, rc.y, psel);
                    }
                    #pragma unroll
                    for (int k = 0; k < 4; ++k)
                        h2 = __hfma2(u2h2(hv4[k]), u2h2(wv4[k]), h2);
                    j += 4;
                }
                for (; j < e; ++j) {
                    const uint2 rc = srec[j];
                    const unsigned hv = Hc32[(rc.x << 6) + lane];
                    const unsigned wv = __builtin_amdgcn_perm(rc.y, rc.y, psel);
                    h2 = __hfma2(u2h2(hv), u2h2(wv), h2);
                }
                a.x += __low2float(h2);
                a.y += __high2float(h2);
            }
            acc[rr] = a;
        }
        __syncthreads();
    }

    // combine channel halves and store (covers zero rows too)
    const int row0 = bucket * RPB + w * 8;
    #pragma unroll
    for (int rr = 0; rr < 8; ++rr) {
        float2 a = acc[rr];
        a.x += __shfl_xor(a.x, 32);
        a.y += __shfl_xor(a.y, 32);
        const int row = row0 + rr;
        if (lane < 32 && row < N) {
            *reinterpret_cast<float2*>(out + (size_t)row * D_OUT + lane * 2) = a;
        }
    }
}

// ---------------------------------------------------------------------------
extern "C" void kernel_launch(void* const* d_in, const int* in_sizes, int n_in,
                              void* d_out, int out_size, void* d_ws, size_t ws_size,
                              hipStream_t stream) {
    const float* H    = (const float*)d_in[0];  // [N,128]
    const float* vals = (const float*)d_in[1];  // [4,E]
    const float* W    = (const float*)d_in[2];  // [2,128,64]
    const float* att  = (const float*)d_in[3];  // [2,128,4]
    const int*   rows = (const int*)d_in[4];    // [4,E]
    const int*   cols = (const int*)d_in[5];    // [4,E]

    const int N    = in_sizes[0] / D_IN;        // 50000
    const int TE   = in_sizes[1];               // 3.2M
    const int Eper = TE / NUM_A;                // 800000
    const int NB   = (N + RPB - 1) / RPB;       // 782

    char* ws = (char*)d_ws;
    size_t off = 0;
    float* ws_score = (float*)(ws + off);          off += 256;
    unsigned short* ws_Hc = (unsigned short*)(ws + off);
    off += (size_t)N * COLS * sizeof(unsigned short);
    off = (off + 255) & ~(size_t)255;
    unsigned* counts  = (unsigned*)(ws + off);     off += (size_t)MAXNB * sizeof(unsigned);
    unsigned* offsets = (unsigned*)(ws + off);     off += (size_t)MAXNB * sizeof(unsigned);
    unsigned* cursor  = (unsigned*)(ws + off);     off += (size_t)MAXNB * sizeof(unsigned);
    off = (off + 255) & ~(size_t)255;
    uint2* erec       = (uint2*)(ws + off);

    // padded path needs NB*CAPB records; fallback needs TE records
    const size_t need_padded = off + (size_t)NB * CAPB * sizeof(uint2);
    const int padded = (ws_size >= need_padded) ? 1 : 0;

    score_kernel<<<1, 64, 0, stream>>>(att, ws_score, padded ? cursor : counts,
                                       NB, padded);

    gemm_kernel<<<(N + 63) / 64, 256, 0, stream>>>(H, W, ws_Hc, N);

    if (!padded) {
        hist_kernel<<<512, 1024, 0, stream>>>(rows, counts, TE, NB);
        scan_kernel<<<1, 1024, 0, stream>>>(counts, offsets, cursor, NB);
    }

    const int sblocks = (TE + SC_CH - 1) / SC_CH;
    scatter_kernel<<<sblocks, SC_T, 0, stream>>>(rows, cols, vals, ws_score,
                                                 cursor, erec, TE, Eper, NB);

    bucketspmm_kernel<<<NB, SPT, 0, stream>>>(erec, offsets, counts, cursor,
                                              (const unsigned*)ws_Hc,
                                              (float*)d_out, N, padded);
}